// Round 4
// baseline (957.881 us; speedup 1.0000x reference)
//
#include <hip/hip_runtime.h>
#include <hip/hip_bf16.h>
#include <math.h>

#define B 64
#define S 64
#define T 21
#define HID 512
#define VOCAB 32000

typedef __bf16 bf16x8 __attribute__((ext_vector_type(8)));
typedef float f32x4 __attribute__((ext_vector_type(4)));

union BF8 { unsigned short u[8]; bf16x8 v; uint4 q; };

__device__ __forceinline__ unsigned short f32_to_bf16_rne(float x) {
    union { float f; unsigned int u; } v;
    v.f = x;
    unsigned int u = v.u;
    unsigned int r = (u + 0x7FFFu + ((u >> 16) & 1u)) >> 16;
    return (unsigned short)r;
}

__device__ __forceinline__ float bf16_to_f32(unsigned short x) {
    union { unsigned int u; float f; } v;
    v.u = ((unsigned int)x) << 16;
    return v.f;
}

__device__ __forceinline__ bf16x8 cvt8(const float* p) {
    float4 f0 = *(const float4*)p;
    float4 f1 = *(const float4*)(p + 4);
    BF8 r;
    r.u[0] = f32_to_bf16_rne(f0.x); r.u[1] = f32_to_bf16_rne(f0.y);
    r.u[2] = f32_to_bf16_rne(f0.z); r.u[3] = f32_to_bf16_rne(f0.w);
    r.u[4] = f32_to_bf16_rne(f1.x); r.u[5] = f32_to_bf16_rne(f1.y);
    r.u[6] = f32_to_bf16_rne(f1.z); r.u[7] = f32_to_bf16_rne(f1.w);
    return r.v;
}

// Coherent (cache-bypassing) u32 load: same mechanism as the working flag
// polls; sees agent-released remote data without any cache-invalidating fence.
__device__ __forceinline__ unsigned ld_u32_coh(const unsigned* p) {
    return __hip_atomic_load(p, __ATOMIC_RELAXED, __HIP_MEMORY_SCOPE_AGENT);
}

// ---------------------------------------------------------------------------
// Fused setup (unchanged). Block ranges:
//  [0,64)       h0 -> hb0 bf16
//  [64,2112)    wc2: [w_ih[:, :512] | w_hh] -> bf16 [n][1024]
//  [2112,2624)  mgemm: M[bs][j] = enc_out . attn_W  (bf16)
//  [2624,3296)  gegemm: geT[t][n][b] = emb(dec_in) . w_ih[:,512:].T + b_ih + b_hh
// ---------------------------------------------------------------------------
__global__ __launch_bounds__(256) void setup_kernel(
        const float* __restrict__ enc_h, const float* __restrict__ style,
        const float* __restrict__ W_e2d, const float* __restrict__ W_e2d_b,
        const float* __restrict__ enc_out, const float* __restrict__ attn_W,
        const float* __restrict__ w_ih, const float* __restrict__ w_hh,
        const float* __restrict__ emb_table, const int* __restrict__ dec_in,
        const float* __restrict__ b_ih, const float* __restrict__ b_hh,
        unsigned short* __restrict__ hb0, unsigned short* __restrict__ wc2,
        unsigned short* __restrict__ M_bf, float* __restrict__ geT) {
    int bid = blockIdx.x;
    int tid = threadIdx.x;
    __shared__ __attribute__((aligned(16))) float smem[640];

    if (bid < 64) {
        int b = bid;
        for (int i = tid; i < 512; i += 256) smem[i] = enc_h[b * 512 + i];
        if (tid < 128) smem[512 + tid] = style[b * 512 + 384 + tid];
        __syncthreads();
        for (int j = tid; j < 512; j += 256) {
            const float4* w4 = (const float4*)(W_e2d + (size_t)j * 640);
            float acc = 0.f;
#pragma unroll 4
            for (int k4 = 0; k4 < 160; k4++) {
                float4 w = w4[k4];
                float4 iv = *(const float4*)(smem + k4 * 4);
                acc += w.x * iv.x + w.y * iv.y + w.z * iv.z + w.w * iv.w;
            }
            hb0[b * 512 + j] = f32_to_bf16_rne(acc + W_e2d_b[j]);
        }
    } else if (bid < 2112) {
        int n = bid - 64;
        for (int k = tid; k < 1024; k += 256) {
            float v = (k < 512) ? w_ih[(size_t)n * 1024 + k]
                                : w_hh[(size_t)n * 512 + (k - 512)];
            wc2[(size_t)n * 1024 + k] = f32_to_bf16_rne(v);
        }
    } else if (bid < 2624) {
        int idx = bid - 2112;
        int xm = idx & 63, y = idx >> 6;
        int w = tid >> 6, lane = tid & 63;
        int col = lane & 15, kq = lane >> 4;
        int m0 = xm * 64 + w * 16;

        bf16x8 af[16];
        const float* arow = enc_out + (size_t)(m0 + col) * 512 + kq * 8;
#pragma unroll
        for (int ks = 0; ks < 16; ks++) af[ks] = cvt8(arow + ks * 32);

#pragma unroll
        for (int nt = 0; nt < 4; nt++) {
            int j0 = y * 64 + nt * 16;
            const float* brow = attn_W + (size_t)(j0 + col) * 512 + kq * 8;
            f32x4 acc = {0.f, 0.f, 0.f, 0.f};
#pragma unroll
            for (int ks = 0; ks < 16; ks++) {
                bf16x8 bf = cvt8(brow + ks * 32);
                acc = __builtin_amdgcn_mfma_f32_16x16x32_bf16(af[ks], bf, acc, 0, 0, 0);
            }
#pragma unroll
            for (int reg = 0; reg < 4; reg++) {
                int m = m0 + kq * 4 + reg;
                M_bf[(size_t)m * 512 + j0 + col] = f32_to_bf16_rne(acc[reg]);
            }
        }
    } else {
        int idx = bid - 2624;
        int mi = idx / 32, ni = idx - mi * 32;   // 21 m-tiles x 32 n-tiles
        int w = tid >> 6, lane = tid & 63;
        int col = lane & 15, kq = lane >> 4;
        int m0 = mi * 64 + w * 16;

        bf16x8 af[16];
        {
            int bt = m0 + col;
            int tok = dec_in[bt];
            const float* arow = emb_table + (size_t)tok * 512 + kq * 8;
#pragma unroll
            for (int ks = 0; ks < 16; ks++) af[ks] = cvt8(arow + ks * 32);
        }
#pragma unroll
        for (int nt = 0; nt < 4; nt++) {
            int n0 = ni * 64 + nt * 16;
            const float* brow = w_ih + (size_t)(n0 + col) * 1024 + 512 + kq * 8;
            f32x4 acc = {0.f, 0.f, 0.f, 0.f};
#pragma unroll
            for (int ks = 0; ks < 16; ks++) {
                bf16x8 bf = cvt8(brow + ks * 32);
                acc = __builtin_amdgcn_mfma_f32_16x16x32_bf16(af[ks], bf, acc, 0, 0, 0);
            }
#pragma unroll
            for (int reg = 0; reg < 4; reg++) {
                int m = m0 + kq * 4 + reg;      // bt index
                int n = n0 + col;
                int bb = m / T, tt = m - bb * T;
                geT[((size_t)tt * 2048 + n) * 64 + bb] = acc[reg] + b_ih[n] + b_hh[n];
            }
        }
    }
}

// ---------------------------------------------------------------------------
// Persistent scan: grid(64) cooperative, block(256).
// NO acquire fences (they invalidate the per-XCD L1/L2 every step, evicting
// enc_out/M/W/geT warm lines). Remote-written data (hb, ctxb) is read with
// cache-bypassing relaxed-agent atomic u32 loads instead — the same
// mechanism the flag polls already use. Producer release-stores (unchanged)
// write back to the agent coherence point.
// ---------------------------------------------------------------------------
__global__ __launch_bounds__(256, 1) void scan_kernel(
        const unsigned short* __restrict__ M_bf,
        const float* __restrict__ enc_out,
        const unsigned short* __restrict__ wc2,
        const float* __restrict__ geT,
        unsigned short* __restrict__ hb0, unsigned short* __restrict__ hb1,
        unsigned short* __restrict__ ctxb, unsigned short* __restrict__ hseqb,
        unsigned* __restrict__ flags) {
    const int bk = blockIdx.x;
    const int tid = threadIdx.x;
    const int b = bk, u0 = bk * 8;
    const int lane = tid & 63, w = tid >> 6;
    const int col = lane & 15, kq = lane >> 4;

    __shared__ __attribute__((aligned(16))) unsigned short Mlds[64 * 512];
    __shared__ __attribute__((aligned(16))) unsigned short Wlds[32 * 1024];
    __shared__ __attribute__((aligned(16))) float fscr[2112];
    __shared__ float scp[4][64];
    __shared__ float hls[512];

    // Stage M[b] (swizzled: chunk' = c ^ (row&7))
#pragma unroll
    for (int i = 0; i < 16; i++) {
        int idx = i * 256 + tid;
        int r = idx >> 6, c = idx & 63;
        *(uint4*)(Mlds + r * 512 + ((c ^ (r & 7)) * 8)) =
            *(const uint4*)(M_bf + ((size_t)(b * 64 + r)) * 512 + c * 8);
    }
    // Stage W rows (swizzled)
#pragma unroll
    for (int i = 0; i < 16; i++) {
        int idx = i * 256 + tid;
        int r = idx >> 7, c = idx & 127;
        int gr = (r >> 3) * 512 + u0 + (r & 7);
        *(uint4*)(Wlds + r * 1024 + ((c ^ (r & 7)) * 8)) =
            *(const uint4*)(wc2 + (size_t)gr * 1024 + c * 8);
    }

    // In-register LSTM lane mapping: lane (col,kq) handles unit u0+(col&7),
    // batches b0+{0,1} (col<8) or b0+{2,3} (col>=8).
    float creg0 = 0.f, creg1 = 0.f;
    const int uloc = col & 7;
    const bool r01 = (col < 8);
    const int b0 = w * 16 + kq * 4;
    __syncthreads();

    unsigned bcnt = 0;
    for (int t = 0; t < T; t++) {
        unsigned short* hcur = (t & 1) ? hb1 : hb0;
        unsigned short* hnxt = (t & 1) ? hb0 : hb1;

        // ---- step-start loads (coherent: hb is remote-written) ----
        unsigned hw = ld_u32_coh((const unsigned*)hcur + b * 256 + tid);
        uint4 hfr[16];
        {
            const unsigned* arow_h =
                (const unsigned*)hcur + (size_t)(w * 16 + col) * 256 + kq * 4;
#pragma unroll
            for (int j = 0; j < 16; j++) {
                hfr[j].x = ld_u32_coh(arow_h + j * 16 + 0);
                hfr[j].y = ld_u32_coh(arow_h + j * 16 + 1);
                hfr[j].z = ld_u32_coh(arow_h + j * 16 + 2);
                hfr[j].w = ld_u32_coh(arow_h + j * 16 + 3);
            }
        }
        const float* ge = geT + (size_t)t * 2048 * 64;
        const int gA = r01 ? 0 : 1, gB = r01 ? 2 : 3;
        float4 geA4 = *(const float4*)(ge + (size_t)(gA * 512 + u0 + uloc) * 64 + b0);
        float4 geB4 = *(const float4*)(ge + (size_t)(gB * 512 + u0 + uloc) * 64 + b0);
        hls[2 * tid]     = bf16_to_f32((unsigned short)(hw & 0xffffu));
        hls[2 * tid + 1] = bf16_to_f32((unsigned short)(hw >> 16));
        __syncthreads();

        // ---------------- phase 1: attention for batch b ----------------
        {   // scores: s = lane, q = w covers d-range q*128..+128
            float acc = 0.f;
#pragma unroll
            for (int i = 0; i < 16; i++) {
                int c = w * 16 + i;
                BF8 mp;
                mp.q = *(const uint4*)(Mlds + lane * 512 + ((c ^ (lane & 7)) * 8));
                const float* hq = hls + w * 128 + i * 8;
#pragma unroll
                for (int j = 0; j < 8; j++) acc += bf16_to_f32(mp.u[j]) * hq[j];
            }
            scp[w][lane] = acc;
        }
        __syncthreads();
        // redundant per-wave softmax (identical ops/results in every wave)
        float a_l;
        {
            float v = scp[0][lane] + scp[1][lane] + scp[2][lane] + scp[3][lane];
            float m = v;
            for (int off = 32; off > 0; off >>= 1) m = fmaxf(m, __shfl_xor(m, off, 64));
            float e = __expf(v - m);
            float ss = e;
            for (int off = 32; off > 0; off >>= 1) ss += __shfl_xor(ss, off, 64);
            a_l = e / ss;
        }
        {   // ctx partials: w covers s-range, lane covers d = lane*8..+8
            float cp[8] = {0, 0, 0, 0, 0, 0, 0, 0};
#pragma unroll 4
            for (int si = 0; si < 16; si++) {
                int s = w * 16 + si;
                float a = __shfl(a_l, s, 64);
                const float* ep = enc_out + ((size_t)(b * 64 + s)) * 512 + lane * 8;
                float4 e0 = *(const float4*)ep;
                float4 e1 = *(const float4*)(ep + 4);
                cp[0] += a * e0.x; cp[1] += a * e0.y; cp[2] += a * e0.z; cp[3] += a * e0.w;
                cp[4] += a * e1.x; cp[5] += a * e1.y; cp[6] += a * e1.z; cp[7] += a * e1.w;
            }
            // lane-major, stride 66: conflict-free writes and reads
#pragma unroll
            for (int j = 0; j < 8; j++) fscr[w * 528 + j * 66 + lane] = cp[j];
        }
        __syncthreads();
        {   // reduce 4 partials, write ctx (bf16, packed u32 stores)
            int l0 = tid >> 2, j0 = (2 * tid) & 7;
            float v0 = fscr[j0 * 66 + l0] + fscr[528 + j0 * 66 + l0] +
                       fscr[1056 + j0 * 66 + l0] + fscr[1584 + j0 * 66 + l0];
            float v1 = fscr[(j0 + 1) * 66 + l0] + fscr[528 + (j0 + 1) * 66 + l0] +
                       fscr[1056 + (j0 + 1) * 66 + l0] + fscr[1584 + (j0 + 1) * 66 + l0];
            unsigned pack = (unsigned)f32_to_bf16_rne(v0) |
                            ((unsigned)f32_to_bf16_rne(v1) << 16);
            *(unsigned*)(ctxb + b * 512 + tid * 2) = pack;
        }

        // ---- barrier 1: arrive (own flag line), per-wave partial wait ----
        bcnt++;
        __syncthreads();
        if (tid == 0)
            __hip_atomic_store(&flags[bk * 32], bcnt, __ATOMIC_RELEASE,
                               __HIP_MEMORY_SCOPE_AGENT);
        if (kq == 0) {   // lanes 0..15 of each wave poll its 16 producers
            const unsigned* f = &flags[(w * 16 + col) * 32];
            while (__hip_atomic_load(f, __ATOMIC_RELAXED, __HIP_MEMORY_SCOPE_AGENT) < bcnt)
                __builtin_amdgcn_s_sleep(2);
        }
        // no fence: ctx read below uses coherent loads

        // ---------------- phase 3: gates MFMA + in-register LSTM ----------------
        f32x4 acc0 = {0.f, 0.f, 0.f, 0.f};
        f32x4 acc1 = {0.f, 0.f, 0.f, 0.f};
        {
            uint4 cfr[16];
            const unsigned* arow_c =
                (const unsigned*)ctxb + (size_t)(w * 16 + col) * 256 + kq * 4;
#pragma unroll
            for (int j = 0; j < 16; j++) {
                cfr[j].x = ld_u32_coh(arow_c + j * 16 + 0);
                cfr[j].y = ld_u32_coh(arow_c + j * 16 + 1);
                cfr[j].z = ld_u32_coh(arow_c + j * 16 + 2);
                cfr[j].w = ld_u32_coh(arow_c + j * 16 + 3);
            }

            int sw0 = col & 7;
            // h-part first: register operands, overlaps the cfr load latency
#pragma unroll
            for (int ks = 16; ks < 32; ks++) {
                BF8 a8; a8.q = hfr[ks - 16];
                int c = kq + 4 * ks;
                bf16x8 bf0 = *reinterpret_cast<const bf16x8*>(
                    Wlds + col * 1024 + ((c ^ sw0) * 8));
                bf16x8 bf1 = *reinterpret_cast<const bf16x8*>(
                    Wlds + (16 + col) * 1024 + ((c ^ sw0) * 8));
                acc0 = __builtin_amdgcn_mfma_f32_16x16x32_bf16(a8.v, bf0, acc0, 0, 0, 0);
                acc1 = __builtin_amdgcn_mfma_f32_16x16x32_bf16(a8.v, bf1, acc1, 0, 0, 0);
            }
#pragma unroll
            for (int ks = 0; ks < 16; ks++) {
                BF8 a8; a8.q = cfr[ks];
                int c = kq + 4 * ks;
                bf16x8 bf0 = *reinterpret_cast<const bf16x8*>(
                    Wlds + col * 1024 + ((c ^ sw0) * 8));
                bf16x8 bf1 = *reinterpret_cast<const bf16x8*>(
                    Wlds + (16 + col) * 1024 + ((c ^ sw0) * 8));
                acc0 = __builtin_amdgcn_mfma_f32_16x16x32_bf16(a8.v, bf0, acc0, 0, 0, 0);
                acc1 = __builtin_amdgcn_mfma_f32_16x16x32_bf16(a8.v, bf1, acc1, 0, 0, 0);
            }
        }
        {   // gates: D row (kq*4+reg)=batch, col<8 -> gate0/2 unit col,
            // col>=8 -> gate1/3 unit col-8. Exchange with partner lane^8.
            float go0[4], go1[4];
            float geAv[4] = {geA4.x, geA4.y, geA4.z, geA4.w};
            float geBv[4] = {geB4.x, geB4.y, geB4.z, geB4.w};
#pragma unroll
            for (int rg = 0; rg < 4; rg++) {
                go0[rg] = acc0[rg] + geAv[rg];
                go1[rg] = acc1[rg] + geBv[rg];
            }
            float sh0 = __shfl_xor(r01 ? go0[2] : go0[0], 8, 64);
            float sh1 = __shfl_xor(r01 ? go0[3] : go0[1], 8, 64);
            float sh2 = __shfl_xor(r01 ? go1[2] : go1[0], 8, 64);
            float sh3 = __shfl_xor(r01 ? go1[3] : go1[1], 8, 64);
            int u = u0 + uloc;
            int bA = b0 + (r01 ? 0 : 2);
            {
                float G0 = r01 ? go0[0] : sh0;
                float G1 = r01 ? sh0 : go0[2];
                float G2 = r01 ? go1[0] : sh2;
                float G3 = r01 ? sh2 : go1[2];
                float ig = 1.f / (1.f + __expf(-G0));
                float fg = 1.f / (1.f + __expf(-G1));
                float gt = tanhf(G2);
                float og = 1.f / (1.f + __expf(-G3));
                creg0 = fg * creg0 + ig * gt;
                float hn = og * tanhf(creg0);
                unsigned short hv = f32_to_bf16_rne(hn);
                hnxt[bA * 512 + u] = hv;
                hseqb[((size_t)bA * T + t) * 512 + u] = hv;
            }
            {
                float G0 = r01 ? go0[1] : sh1;
                float G1 = r01 ? sh1 : go0[3];
                float G2 = r01 ? go1[1] : sh3;
                float G3 = r01 ? sh3 : go1[3];
                float ig = 1.f / (1.f + __expf(-G0));
                float fg = 1.f / (1.f + __expf(-G1));
                float gt = tanhf(G2);
                float og = 1.f / (1.f + __expf(-G3));
                creg1 = fg * creg1 + ig * gt;
                float hn = og * tanhf(creg1);
                unsigned short hv = f32_to_bf16_rne(hn);
                int bB = bA + 1;
                hnxt[bB * 512 + u] = hv;
                hseqb[((size_t)bB * T + t) * 512 + u] = hv;
            }
        }

        // ---- barrier 2: full (h is all-to-all); skip after last step ----
        bcnt++;
        if (t < T - 1) {
            __syncthreads();
            if (tid == 0)
                __hip_atomic_store(&flags[bk * 32], bcnt, __ATOMIC_RELEASE,
                                   __HIP_MEMORY_SCOPE_AGENT);
            if (tid < 64) {
                const unsigned* f = &flags[tid * 32];
                while (__hip_atomic_load(f, __ATOMIC_RELAXED, __HIP_MEMORY_SCOPE_AGENT) < bcnt)
                    __builtin_amdgcn_s_sleep(2);
            }
            // no fence: next step's hb reads use coherent loads
            __syncthreads();
        }
    }
}

// ---------------------------------------------------------------------------
// Projection + exp-sum (known-good single-buffer form).
// grid(500), block(256). Wave wv: nhalf = wv&1, mhalf = wv>>1. hseq tile in
// XOR-swizzled LDS; 1 ds_read feeds 2 MFMAs. Epilogue: 8 exps -> one LDS
// atomicAdd per lane per tile.
// ---------------------------------------------------------------------------
__global__ __launch_bounds__(256) void proj_mfma_kernel(
        const unsigned short* __restrict__ hseqb,
        const float* __restrict__ proj_w,
        const float* __restrict__ proj_b,
        float* __restrict__ partial) {
    int tid = threadIdx.x;
    int wv = tid >> 6, lane = tid & 63;
    int col = lane & 15, kq = lane >> 4;
    int nhalf = wv & 1, mhalf = wv >> 1;
    int n0 = blockIdx.x * 64 + nhalf * 32;

    bf16x8 Af0[16], Af1[16];
    {
        const float* w0 = proj_w + (size_t)(n0 + col) * 512 + kq * 8;
        const float* w1 = proj_w + (size_t)(n0 + 16 + col) * 512 + kq * 8;
#pragma unroll
        for (int ks = 0; ks < 16; ks++) {
            Af0[ks] = cvt8(w0 + ks * 32);
            Af1[ks] = cvt8(w1 + ks * 32);
        }
    }
    float4 bias0 = *(const float4*)(proj_b + n0 + kq * 4);
    float4 bias1 = *(const float4*)(proj_b + n0 + 16 + kq * 4);

    __shared__ __attribute__((aligned(16))) unsigned short alds[32 * 512];
    __shared__ float esum[1344];
    for (int i = tid; i < 1344; i += 256) esum[i] = 0.f;
    __syncthreads();

    for (int mt = 0; mt < 42; mt++) {
        int mA = mt * 32;
        __syncthreads();
#pragma unroll
        for (int i = 0; i < 8; i++) {
            int idx = i * 256 + tid;
            int r = idx >> 6, c = idx & 63;
            *(uint4*)(alds + r * 512 + ((c ^ (r & 7)) * 8)) =
                *(const uint4*)(hseqb + (size_t)(mA + r) * 512 + c * 8);
        }
        __syncthreads();
        int rr = mhalf * 16 + col;
        int sw = rr & 7;
        f32x4 acc0 = {0.f, 0.f, 0.f, 0.f};
        f32x4 acc1 = {0.f, 0.f, 0.f, 0.f};
#pragma unroll
        for (int ks = 0; ks < 16; ks++) {
            int c = kq + 4 * ks;
            bf16x8 bf = *reinterpret_cast<const bf16x8*>(
                alds + rr * 512 + ((c ^ sw) * 8));
            acc0 = __builtin_amdgcn_mfma_f32_16x16x32_bf16(Af0[ks], bf, acc0, 0, 0, 0);
            acc1 = __builtin_amdgcn_mfma_f32_16x16x32_bf16(Af1[ks], bf, acc1, 0, 0, 0);
        }
        float e = __expf(acc0[0] + bias0.x) + __expf(acc0[1] + bias0.y) +
                  __expf(acc0[2] + bias0.z) + __expf(acc0[3] + bias0.w) +
                  __expf(acc1[0] + bias1.x) + __expf(acc1[1] + bias1.y) +
                  __expf(acc1[2] + bias1.z) + __expf(acc1[3] + bias1.w);
        atomicAdd(&esum[mA + rr], e);
    }
    __syncthreads();
    for (int i = tid; i < 1344; i += 256)
        partial[(size_t)blockIdx.x * 1344 + i] = esum[i];
}

// ---------------------------------------------------------------------------
__global__ __launch_bounds__(256) void sumexp_reduce_kernel(
        const float* __restrict__ partial, float* __restrict__ sumexp) {
    int m = blockIdx.x * 32 + (threadIdx.x >> 3);
    int sub = threadIdx.x & 7;
    float s = 0.f;
    for (int nb = sub; nb < 500; nb += 8) s += partial[(size_t)nb * 1344 + m];
    s += __shfl_xor(s, 1, 64);
    s += __shfl_xor(s, 2, 64);
    s += __shfl_xor(s, 4, 64);
    if (sub == 0) sumexp[m] = s;
}

// ---------------------------------------------------------------------------
__global__ __launch_bounds__(64) void loss_kernel(
        const unsigned short* __restrict__ hseqb,
        const float* __restrict__ proj_w, const float* __restrict__ proj_b,
        const float* __restrict__ sumexp, const int* __restrict__ seq_label,
        float* __restrict__ out) {
    int b = blockIdx.x;
    int lane = threadIdx.x;
    float num = 0.f, den = 0.f;
    for (int t = 0; t < T; t++) {
        int label = seq_label[b * T + t];
        const unsigned short* hp = hseqb + ((size_t)b * T + t) * 512;
        const float* wp = proj_w + (size_t)label * 512;
        float acc = 0.f;
#pragma unroll
        for (int i = 0; i < 8; i++)
            acc += bf16_to_f32(hp[lane + 64 * i]) * wp[lane + 64 * i];
        for (int off = 32; off > 0; off >>= 1) acc += __shfl_xor(acc, off, 64);
        if (lane == 0) {
            float nll = logf(sumexp[b * T + t]) - (acc + proj_b[label]);
            float mask = (label > 0) ? 1.f : 0.f;
            num += mask * nll;
            den += mask;
        }
    }
    if (lane == 0) atomicAdd(out, (num / (den + 1e-6f)) * (1.f / 64.f));
}

// ---------------------------------------------------------------------------
extern "C" void kernel_launch(void* const* d_in, const int* in_sizes, int n_in,
                              void* d_out, int out_size, void* d_ws, size_t ws_size,
                              hipStream_t stream) {
    const float* enc_h     = (const float*)d_in[0];
    const float* enc_out   = (const float*)d_in[1];
    const int*   seq_label = (const int*)d_in[3];
    const int*   dec_in    = (const int*)d_in[4];
    const float* style     = (const float*)d_in[5];
    const float* W_e2d_w   = (const float*)d_in[6];
    const float* W_e2d_b   = (const float*)d_in[7];
    const float* attn_W    = (const float*)d_in[8];
    const float* emb_table = (const float*)d_in[9];
    const float* w_ih      = (const float*)d_in[10];
    const float* w_hh      = (const float*)d_in[11];
    const float* b_ih      = (const float*)d_in[12];
    const float* b_hh      = (const float*)d_in[13];
    const float* proj_w    = (const float*)d_in[14];
    const float* proj_b    = (const float*)d_in[15];
    float* out = (float*)d_out;

    char* p = (char*)d_ws;
    float* partial = (float*)p;                    p += 500 * 1344 * 4;
    float* sumexp  = (float*)p;                    p += 1344 * 4 + 64;
    float* geT     = (float*)p;                    p += (size_t)21 * 2048 * 64 * 4;
    unsigned short* M_bf  = (unsigned short*)p;    p += (size_t)4096 * 512 * 2;
    unsigned short* wc2   = (unsigned short*)p;    p += (size_t)2048 * 1024 * 2;
    unsigned short* hseqb = (unsigned short*)p;    p += (size_t)1344 * 512 * 2;
    unsigned short* hb0   = (unsigned short*)p;    p += 64 * 512 * 2;
    unsigned short* hb1   = (unsigned short*)p;    p += 64 * 512 * 2;
    unsigned short* ctxb  = (unsigned short*)p;    p += 64 * 512 * 2;
    unsigned* bar = (unsigned*)p;                  p += 64 * 32 * 4;   // 64 flag lines

    hipMemsetAsync(out, 0, sizeof(float), stream);
    hipMemsetAsync(bar, 0, 64 * 32 * 4, stream);

    setup_kernel<<<3296, 256, 0, stream>>>(enc_h, style, W_e2d_w, W_e2d_b,
                                           enc_out, attn_W, w_ih, w_hh,
                                           emb_table, dec_in, b_ih, b_hh,
                                           hb0, wc2, M_bf, geT);

    {
        void* args[] = {(void*)&M_bf, (void*)&enc_out, (void*)&wc2, (void*)&geT,
                        (void*)&hb0, (void*)&hb1, (void*)&ctxb, (void*)&hseqb,
                        (void*)&bar};
        hipLaunchCooperativeKernel((const void*)scan_kernel, dim3(64),
                                   dim3(256), args, 0, stream);
    }

    proj_mfma_kernel<<<500, 256, 0, stream>>>(hseqb, proj_w, proj_b, partial);
    sumexp_reduce_kernel<<<42, 256, 0, stream>>>(partial, sumexp);
    loss_kernel<<<64, 64, 0, stream>>>(hseqb, proj_w, proj_b, sumexp, seq_label, out);
}

// Round 5
// 801.161 us; speedup vs baseline: 1.1956x; 1.1956x over previous
//
#include <hip/hip_runtime.h>
#include <hip/hip_bf16.h>
#include <math.h>

#define B 64
#define S 64
#define T 21
#define HID 512
#define VOCAB 32000

typedef __bf16 bf16x8 __attribute__((ext_vector_type(8)));
typedef float f32x4 __attribute__((ext_vector_type(4)));

union BF8 { unsigned short u[8]; bf16x8 v; uint4 q; };

__device__ __forceinline__ unsigned short f32_to_bf16_rne(float x) {
    union { float f; unsigned int u; } v;
    v.f = x;
    unsigned int u = v.u;
    unsigned int r = (u + 0x7FFFu + ((u >> 16) & 1u)) >> 16;
    return (unsigned short)r;
}

__device__ __forceinline__ float bf16_to_f32(unsigned short x) {
    union { unsigned int u; float f; } v;
    v.u = ((unsigned int)x) << 16;
    return v.f;
}

__device__ __forceinline__ bf16x8 cvt8(const float* p) {
    float4 f0 = *(const float4*)p;
    float4 f1 = *(const float4*)(p + 4);
    BF8 r;
    r.u[0] = f32_to_bf16_rne(f0.x); r.u[1] = f32_to_bf16_rne(f0.y);
    r.u[2] = f32_to_bf16_rne(f0.z); r.u[3] = f32_to_bf16_rne(f0.w);
    r.u[4] = f32_to_bf16_rne(f1.x); r.u[5] = f32_to_bf16_rne(f1.y);
    r.u[6] = f32_to_bf16_rne(f1.z); r.u[7] = f32_to_bf16_rne(f1.w);
    return r.v;
}

// ---------------------------------------------------------------------------
// Fused setup (unchanged). Block ranges:
//  [0,64)       h0 -> hb0 bf16
//  [64,2112)    wc2: [w_ih[:, :512] | w_hh] -> bf16 [n][1024]
//  [2112,2624)  mgemm: M[bs][j] = enc_out . attn_W  (bf16)
//  [2624,3296)  gegemm: geT[t][n][b] = emb(dec_in) . w_ih[:,512:].T + b_ih + b_hh
// ---------------------------------------------------------------------------
__global__ __launch_bounds__(256) void setup_kernel(
        const float* __restrict__ enc_h, const float* __restrict__ style,
        const float* __restrict__ W_e2d, const float* __restrict__ W_e2d_b,
        const float* __restrict__ enc_out, const float* __restrict__ attn_W,
        const float* __restrict__ w_ih, const float* __restrict__ w_hh,
        const float* __restrict__ emb_table, const int* __restrict__ dec_in,
        const float* __restrict__ b_ih, const float* __restrict__ b_hh,
        unsigned short* __restrict__ hb0, unsigned short* __restrict__ wc2,
        unsigned short* __restrict__ M_bf, float* __restrict__ geT) {
    int bid = blockIdx.x;
    int tid = threadIdx.x;
    __shared__ __attribute__((aligned(16))) float smem[640];

    if (bid < 64) {
        int b = bid;
        for (int i = tid; i < 512; i += 256) smem[i] = enc_h[b * 512 + i];
        if (tid < 128) smem[512 + tid] = style[b * 512 + 384 + tid];
        __syncthreads();
        for (int j = tid; j < 512; j += 256) {
            const float4* w4 = (const float4*)(W_e2d + (size_t)j * 640);
            float acc = 0.f;
#pragma unroll 4
            for (int k4 = 0; k4 < 160; k4++) {
                float4 w = w4[k4];
                float4 iv = *(const float4*)(smem + k4 * 4);
                acc += w.x * iv.x + w.y * iv.y + w.z * iv.z + w.w * iv.w;
            }
            hb0[b * 512 + j] = f32_to_bf16_rne(acc + W_e2d_b[j]);
        }
    } else if (bid < 2112) {
        int n = bid - 64;
        for (int k = tid; k < 1024; k += 256) {
            float v = (k < 512) ? w_ih[(size_t)n * 1024 + k]
                                : w_hh[(size_t)n * 512 + (k - 512)];
            wc2[(size_t)n * 1024 + k] = f32_to_bf16_rne(v);
        }
    } else if (bid < 2624) {
        int idx = bid - 2112;
        int xm = idx & 63, y = idx >> 6;
        int w = tid >> 6, lane = tid & 63;
        int col = lane & 15, kq = lane >> 4;
        int m0 = xm * 64 + w * 16;

        bf16x8 af[16];
        const float* arow = enc_out + (size_t)(m0 + col) * 512 + kq * 8;
#pragma unroll
        for (int ks = 0; ks < 16; ks++) af[ks] = cvt8(arow + ks * 32);

#pragma unroll
        for (int nt = 0; nt < 4; nt++) {
            int j0 = y * 64 + nt * 16;
            const float* brow = attn_W + (size_t)(j0 + col) * 512 + kq * 8;
            f32x4 acc = {0.f, 0.f, 0.f, 0.f};
#pragma unroll
            for (int ks = 0; ks < 16; ks++) {
                bf16x8 bf = cvt8(brow + ks * 32);
                acc = __builtin_amdgcn_mfma_f32_16x16x32_bf16(af[ks], bf, acc, 0, 0, 0);
            }
#pragma unroll
            for (int reg = 0; reg < 4; reg++) {
                int m = m0 + kq * 4 + reg;
                M_bf[(size_t)m * 512 + j0 + col] = f32_to_bf16_rne(acc[reg]);
            }
        }
    } else {
        int idx = bid - 2624;
        int mi = idx / 32, ni = idx - mi * 32;   // 21 m-tiles x 32 n-tiles
        int w = tid >> 6, lane = tid & 63;
        int col = lane & 15, kq = lane >> 4;
        int m0 = mi * 64 + w * 16;

        bf16x8 af[16];
        {
            int bt = m0 + col;
            int tok = dec_in[bt];
            const float* arow = emb_table + (size_t)tok * 512 + kq * 8;
#pragma unroll
            for (int ks = 0; ks < 16; ks++) af[ks] = cvt8(arow + ks * 32);
        }
#pragma unroll
        for (int nt = 0; nt < 4; nt++) {
            int n0 = ni * 64 + nt * 16;
            const float* brow = w_ih + (size_t)(n0 + col) * 1024 + 512 + kq * 8;
            f32x4 acc = {0.f, 0.f, 0.f, 0.f};
#pragma unroll
            for (int ks = 0; ks < 16; ks++) {
                bf16x8 bf = cvt8(brow + ks * 32);
                acc = __builtin_amdgcn_mfma_f32_16x16x32_bf16(af[ks], bf, acc, 0, 0, 0);
            }
#pragma unroll
            for (int reg = 0; reg < 4; reg++) {
                int m = m0 + kq * 4 + reg;      // bt index
                int n = n0 + col;
                int bb = m / T, tt = m - bb * T;
                geT[((size_t)tt * 2048 + n) * 64 + bb] = acc[reg] + b_ih[n] + b_hh[n];
            }
        }
    }
}

// ---------------------------------------------------------------------------
// Persistent scan: grid(64) cooperative, block(256).
// R2-proven sync semantics (release-store flags + acquire fences + normal
// vectorized loads). Two additions:
//  - enc_out touch-warm: the bar-2 acquire fence invalidates L1/L2 each
//    step, so phase-1 ctx would re-read 131 KB from L3 serially. 8 touch
//    loads/thread at step start re-warm it under scores+softmax.
//  - bar-1 skew hiding: arrive -> h-part MFMAs (no remote deps) -> poll
//    producers -> acquire fence -> cfr loads -> ctx MFMAs. Accumulation
//    order (h then ctx) unchanged => bit-identical numerics.
// ---------------------------------------------------------------------------
__global__ __launch_bounds__(256, 1) void scan_kernel(
        const unsigned short* __restrict__ M_bf,
        const float* __restrict__ enc_out,
        const unsigned short* __restrict__ wc2,
        const float* __restrict__ geT,
        unsigned short* __restrict__ hb0, unsigned short* __restrict__ hb1,
        unsigned short* __restrict__ ctxb, unsigned short* __restrict__ hseqb,
        unsigned* __restrict__ flags) {
    const int bk = blockIdx.x;
    const int tid = threadIdx.x;
    const int b = bk, u0 = bk * 8;
    const int lane = tid & 63, w = tid >> 6;
    const int col = lane & 15, kq = lane >> 4;

    __shared__ __attribute__((aligned(16))) unsigned short Mlds[64 * 512];
    __shared__ __attribute__((aligned(16))) unsigned short Wlds[32 * 1024];
    __shared__ __attribute__((aligned(16))) float fscr[2112];
    __shared__ float scp[4][64];
    __shared__ float hls[512];

    // Stage M[b] (swizzled: chunk' = c ^ (row&7))
#pragma unroll
    for (int i = 0; i < 16; i++) {
        int idx = i * 256 + tid;
        int r = idx >> 6, c = idx & 63;
        *(uint4*)(Mlds + r * 512 + ((c ^ (r & 7)) * 8)) =
            *(const uint4*)(M_bf + ((size_t)(b * 64 + r)) * 512 + c * 8);
    }
    // Stage W rows (swizzled)
#pragma unroll
    for (int i = 0; i < 16; i++) {
        int idx = i * 256 + tid;
        int r = idx >> 7, c = idx & 127;
        int gr = (r >> 3) * 512 + u0 + (r & 7);
        *(uint4*)(Wlds + r * 1024 + ((c ^ (r & 7)) * 8)) =
            *(const uint4*)(wc2 + (size_t)gr * 1024 + c * 8);
    }

    // In-register LSTM lane mapping: lane (col,kq) handles unit u0+(col&7),
    // batches b0+{0,1} (col<8) or b0+{2,3} (col>=8).
    float creg0 = 0.f, creg1 = 0.f;
    const int uloc = col & 7;
    const bool r01 = (col < 8);
    const int b0 = w * 16 + kq * 4;
    __syncthreads();

    unsigned bcnt = 0;
    for (int t = 0; t < T; t++) {
        unsigned short* hcur = (t & 1) ? hb1 : hb0;
        unsigned short* hnxt = (t & 1) ? hb0 : hb1;

        // ---- step-start loads: hls + phase-3 prefetch + enc_out touch ----
        unsigned hw = *((const unsigned*)hcur + b * 256 + tid);
        uint4 hfr[16];
        {
            const unsigned short* arow_h = hcur + (size_t)(w * 16 + col) * 512 + kq * 8;
#pragma unroll
            for (int j = 0; j < 16; j++) hfr[j] = *(const uint4*)(arow_h + j * 32);
        }
        const float* ge = geT + (size_t)t * 2048 * 64;
        const int gA = r01 ? 0 : 1, gB = r01 ? 2 : 3;
        float4 geA4 = *(const float4*)(ge + (size_t)(gA * 512 + u0 + uloc) * 64 + b0);
        float4 geB4 = *(const float4*)(ge + (size_t)(gB * 512 + u0 + uloc) * 64 + b0);
        // enc_out tile re-warm: one dword per 64B line, 131 KB total
        float tch[8];
        {
            const float* ebase = enc_out + (size_t)b * 32768;
#pragma unroll
            for (int i = 0; i < 8; i++) tch[i] = ebase[(size_t)(i * 256 + tid) * 16];
        }
        hls[2 * tid]     = bf16_to_f32((unsigned short)(hw & 0xffffu));
        hls[2 * tid + 1] = bf16_to_f32((unsigned short)(hw >> 16));
        __syncthreads();

        // ---------------- phase 1: attention for batch b ----------------
        {   // scores: s = lane, q = w covers d-range q*128..+128
            float acc = 0.f;
#pragma unroll
            for (int i = 0; i < 16; i++) {
                int c = w * 16 + i;
                BF8 mp;
                mp.q = *(const uint4*)(Mlds + lane * 512 + ((c ^ (lane & 7)) * 8));
                const float* hq = hls + w * 128 + i * 8;
#pragma unroll
                for (int j = 0; j < 8; j++) acc += bf16_to_f32(mp.u[j]) * hq[j];
            }
            scp[w][lane] = acc;
        }
        __syncthreads();
        // redundant per-wave softmax (identical ops/results in every wave)
        float a_l;
        {
            float v = scp[0][lane] + scp[1][lane] + scp[2][lane] + scp[3][lane];
            float m = v;
            for (int off = 32; off > 0; off >>= 1) m = fmaxf(m, __shfl_xor(m, off, 64));
            float e = __expf(v - m);
            float ss = e;
            for (int off = 32; off > 0; off >>= 1) ss += __shfl_xor(ss, off, 64);
            a_l = e / ss;
        }
        // sink the touch loads (keeps them live; they've completed by now)
#pragma unroll
        for (int i = 0; i < 8; i++) asm volatile("" :: "v"(tch[i]));
        {   // ctx partials: w covers s-range, lane covers d = lane*8..+8
            float cp[8] = {0, 0, 0, 0, 0, 0, 0, 0};
#pragma unroll 4
            for (int si = 0; si < 16; si++) {
                int s = w * 16 + si;
                float a = __shfl(a_l, s, 64);
                const float* ep = enc_out + ((size_t)(b * 64 + s)) * 512 + lane * 8;
                float4 e0 = *(const float4*)ep;
                float4 e1 = *(const float4*)(ep + 4);
                cp[0] += a * e0.x; cp[1] += a * e0.y; cp[2] += a * e0.z; cp[3] += a * e0.w;
                cp[4] += a * e1.x; cp[5] += a * e1.y; cp[6] += a * e1.z; cp[7] += a * e1.w;
            }
            // lane-major, stride 66: conflict-free writes and reads
#pragma unroll
            for (int j = 0; j < 8; j++) fscr[w * 528 + j * 66 + lane] = cp[j];
        }
        __syncthreads();
        {   // reduce 4 partials, write ctx (bf16, packed u32 stores)
            int l0 = tid >> 2, j0 = (2 * tid) & 7;
            float v0 = fscr[j0 * 66 + l0] + fscr[528 + j0 * 66 + l0] +
                       fscr[1056 + j0 * 66 + l0] + fscr[1584 + j0 * 66 + l0];
            float v1 = fscr[(j0 + 1) * 66 + l0] + fscr[528 + (j0 + 1) * 66 + l0] +
                       fscr[1056 + (j0 + 1) * 66 + l0] + fscr[1584 + (j0 + 1) * 66 + l0];
            unsigned pack = (unsigned)f32_to_bf16_rne(v0) |
                            ((unsigned)f32_to_bf16_rne(v1) << 16);
            *(unsigned*)(ctxb + b * 512 + tid * 2) = pack;
        }

        // ---- barrier 1: arrive, then h-MFMAs, then wait + fence ----
        bcnt++;
        __syncthreads();
        if (tid == 0)
            __hip_atomic_store(&flags[bk * 32], bcnt, __ATOMIC_RELEASE,
                               __HIP_MEMORY_SCOPE_AGENT);

        f32x4 acc0 = {0.f, 0.f, 0.f, 0.f};
        f32x4 acc1 = {0.f, 0.f, 0.f, 0.f};
        int sw0 = col & 7;
        // h-part MFMAs first: register/LDS operands only, no remote deps —
        // hides producer skew + flag propagation.
#pragma unroll
        for (int ks = 16; ks < 32; ks++) {
            BF8 a8; a8.q = hfr[ks - 16];
            int c = kq + 4 * ks;
            bf16x8 bf0 = *reinterpret_cast<const bf16x8*>(
                Wlds + col * 1024 + ((c ^ sw0) * 8));
            bf16x8 bf1 = *reinterpret_cast<const bf16x8*>(
                Wlds + (16 + col) * 1024 + ((c ^ sw0) * 8));
            acc0 = __builtin_amdgcn_mfma_f32_16x16x32_bf16(a8.v, bf0, acc0, 0, 0, 0);
            acc1 = __builtin_amdgcn_mfma_f32_16x16x32_bf16(a8.v, bf1, acc1, 0, 0, 0);
        }
        __builtin_amdgcn_sched_barrier(0);   // keep MFMAs before the poll

        if (kq == 0) {   // lanes 0..15 of each wave poll its 16 producers
            const unsigned* f = &flags[(w * 16 + col) * 32];
            while (__hip_atomic_load(f, __ATOMIC_RELAXED, __HIP_MEMORY_SCOPE_AGENT) < bcnt)
                __builtin_amdgcn_s_sleep(2);
        }
        __builtin_amdgcn_fence(__ATOMIC_ACQUIRE, "agent");

        // ---------------- phase 3b: ctx MFMAs + in-register LSTM ----------------
        {
            uint4 cfr[16];
            const unsigned short* arow_c = ctxb + (size_t)(w * 16 + col) * 512 + kq * 8;
#pragma unroll
            for (int j = 0; j < 16; j++) cfr[j] = *(const uint4*)(arow_c + j * 32);

#pragma unroll
            for (int ks = 0; ks < 16; ks++) {
                BF8 a8; a8.q = cfr[ks];
                int c = kq + 4 * ks;
                bf16x8 bf0 = *reinterpret_cast<const bf16x8*>(
                    Wlds + col * 1024 + ((c ^ sw0) * 8));
                bf16x8 bf1 = *reinterpret_cast<const bf16x8*>(
                    Wlds + (16 + col) * 1024 + ((c ^ sw0) * 8));
                acc0 = __builtin_amdgcn_mfma_f32_16x16x32_bf16(a8.v, bf0, acc0, 0, 0, 0);
                acc1 = __builtin_amdgcn_mfma_f32_16x16x32_bf16(a8.v, bf1, acc1, 0, 0, 0);
            }
        }
        {   // gates: D row (kq*4+reg)=batch, col<8 -> gate0/2 unit col,
            // col>=8 -> gate1/3 unit col-8. Exchange with partner lane^8.
            float go0[4], go1[4];
            float geAv[4] = {geA4.x, geA4.y, geA4.z, geA4.w};
            float geBv[4] = {geB4.x, geB4.y, geB4.z, geB4.w};
#pragma unroll
            for (int rg = 0; rg < 4; rg++) {
                go0[rg] = acc0[rg] + geAv[rg];
                go1[rg] = acc1[rg] + geBv[rg];
            }
            float sh0 = __shfl_xor(r01 ? go0[2] : go0[0], 8, 64);
            float sh1 = __shfl_xor(r01 ? go0[3] : go0[1], 8, 64);
            float sh2 = __shfl_xor(r01 ? go1[2] : go1[0], 8, 64);
            float sh3 = __shfl_xor(r01 ? go1[3] : go1[1], 8, 64);
            int u = u0 + uloc;
            int bA = b0 + (r01 ? 0 : 2);
            {
                float G0 = r01 ? go0[0] : sh0;
                float G1 = r01 ? sh0 : go0[2];
                float G2 = r01 ? go1[0] : sh2;
                float G3 = r01 ? sh2 : go1[2];
                float ig = 1.f / (1.f + __expf(-G0));
                float fg = 1.f / (1.f + __expf(-G1));
                float gt = tanhf(G2);
                float og = 1.f / (1.f + __expf(-G3));
                creg0 = fg * creg0 + ig * gt;
                float hn = og * tanhf(creg0);
                unsigned short hv = f32_to_bf16_rne(hn);
                hnxt[bA * 512 + u] = hv;
                hseqb[((size_t)bA * T + t) * 512 + u] = hv;
            }
            {
                float G0 = r01 ? go0[1] : sh1;
                float G1 = r01 ? sh1 : go0[3];
                float G2 = r01 ? go1[1] : sh3;
                float G3 = r01 ? sh3 : go1[3];
                float ig = 1.f / (1.f + __expf(-G0));
                float fg = 1.f / (1.f + __expf(-G1));
                float gt = tanhf(G2);
                float og = 1.f / (1.f + __expf(-G3));
                creg1 = fg * creg1 + ig * gt;
                float hn = og * tanhf(creg1);
                unsigned short hv = f32_to_bf16_rne(hn);
                int bB = bA + 1;
                hnxt[bB * 512 + u] = hv;
                hseqb[((size_t)bB * T + t) * 512 + u] = hv;
            }
        }

        // ---- barrier 2: full (h is all-to-all); skip after last step ----
        bcnt++;
        if (t < T - 1) {
            __syncthreads();
            if (tid == 0)
                __hip_atomic_store(&flags[bk * 32], bcnt, __ATOMIC_RELEASE,
                                   __HIP_MEMORY_SCOPE_AGENT);
            if (tid < 64) {
                const unsigned* f = &flags[tid * 32];
                while (__hip_atomic_load(f, __ATOMIC_RELAXED, __HIP_MEMORY_SCOPE_AGENT) < bcnt)
                    __builtin_amdgcn_s_sleep(2);
            }
            __builtin_amdgcn_fence(__ATOMIC_ACQUIRE, "agent");
            __syncthreads();
        }
    }
}

// ---------------------------------------------------------------------------
// Projection + exp-sum (known-good single-buffer form).
// grid(500), block(256). Wave wv: nhalf = wv&1, mhalf = wv>>1. hseq tile in
// XOR-swizzled LDS; 1 ds_read feeds 2 MFMAs. Epilogue: 8 exps -> one LDS
// atomicAdd per lane per tile.
// ---------------------------------------------------------------------------
__global__ __launch_bounds__(256) void proj_mfma_kernel(
        const unsigned short* __restrict__ hseqb,
        const float* __restrict__ proj_w,
        const float* __restrict__ proj_b,
        float* __restrict__ partial) {
    int tid = threadIdx.x;
    int wv = tid >> 6, lane = tid & 63;
    int col = lane & 15, kq = lane >> 4;
    int nhalf = wv & 1, mhalf = wv >> 1;
    int n0 = blockIdx.x * 64 + nhalf * 32;

    bf16x8 Af0[16], Af1[16];
    {
        const float* w0 = proj_w + (size_t)(n0 + col) * 512 + kq * 8;
        const float* w1 = proj_w + (size_t)(n0 + 16 + col) * 512 + kq * 8;
#pragma unroll
        for (int ks = 0; ks < 16; ks++) {
            Af0[ks] = cvt8(w0 + ks * 32);
            Af1[ks] = cvt8(w1 + ks * 32);
        }
    }
    float4 bias0 = *(const float4*)(proj_b + n0 + kq * 4);
    float4 bias1 = *(const float4*)(proj_b + n0 + 16 + kq * 4);

    __shared__ __attribute__((aligned(16))) unsigned short alds[32 * 512];
    __shared__ float esum[1344];
    for (int i = tid; i < 1344; i += 256) esum[i] = 0.f;
    __syncthreads();

    for (int mt = 0; mt < 42; mt++) {
        int mA = mt * 32;
        __syncthreads();
#pragma unroll
        for (int i = 0; i < 8; i++) {
            int idx = i * 256 + tid;
            int r = idx >> 6, c = idx & 63;
            *(uint4*)(alds + r * 512 + ((c ^ (r & 7)) * 8)) =
                *(const uint4*)(hseqb + (size_t)(mA + r) * 512 + c * 8);
        }
        __syncthreads();
        int rr = mhalf * 16 + col;
        int sw = rr & 7;
        f32x4 acc0 = {0.f, 0.f, 0.f, 0.f};
        f32x4 acc1 = {0.f, 0.f, 0.f, 0.f};
#pragma unroll
        for (int ks = 0; ks < 16; ks++) {
            int c = kq + 4 * ks;
            bf16x8 bf = *reinterpret_cast<const bf16x8*>(
                alds + rr * 512 + ((c ^ sw) * 8));
            acc0 = __builtin_amdgcn_mfma_f32_16x16x32_bf16(Af0[ks], bf, acc0, 0, 0, 0);
            acc1 = __builtin_amdgcn_mfma_f32_16x16x32_bf16(Af1[ks], bf, acc1, 0, 0, 0);
        }
        float e = __expf(acc0[0] + bias0.x) + __expf(acc0[1] + bias0.y) +
                  __expf(acc0[2] + bias0.z) + __expf(acc0[3] + bias0.w) +
                  __expf(acc1[0] + bias1.x) + __expf(acc1[1] + bias1.y) +
                  __expf(acc1[2] + bias1.z) + __expf(acc1[3] + bias1.w);
        atomicAdd(&esum[mA + rr], e);
    }
    __syncthreads();
    for (int i = tid; i < 1344; i += 256)
        partial[(size_t)blockIdx.x * 1344 + i] = esum[i];
}

// ---------------------------------------------------------------------------
__global__ __launch_bounds__(256) void sumexp_reduce_kernel(
        const float* __restrict__ partial, float* __restrict__ sumexp) {
    int m = blockIdx.x * 32 + (threadIdx.x >> 3);
    int sub = threadIdx.x & 7;
    float s = 0.f;
    for (int nb = sub; nb < 500; nb += 8) s += partial[(size_t)nb * 1344 + m];
    s += __shfl_xor(s, 1, 64);
    s += __shfl_xor(s, 2, 64);
    s += __shfl_xor(s, 4, 64);
    if (sub == 0) sumexp[m] = s;
}

// ---------------------------------------------------------------------------
__global__ __launch_bounds__(64) void loss_kernel(
        const unsigned short* __restrict__ hseqb,
        const float* __restrict__ proj_w, const float* __restrict__ proj_b,
        const float* __restrict__ sumexp, const int* __restrict__ seq_label,
        float* __restrict__ out) {
    int b = blockIdx.x;
    int lane = threadIdx.x;
    float num = 0.f, den = 0.f;
    for (int t = 0; t < T; t++) {
        int label = seq_label[b * T + t];
        const unsigned short* hp = hseqb + ((size_t)b * T + t) * 512;
        const float* wp = proj_w + (size_t)label * 512;
        float acc = 0.f;
#pragma unroll
        for (int i = 0; i < 8; i++)
            acc += bf16_to_f32(hp[lane + 64 * i]) * wp[lane + 64 * i];
        for (int off = 32; off > 0; off >>= 1) acc += __shfl_xor(acc, off, 64);
        if (lane == 0) {
            float nll = logf(sumexp[b * T + t]) - (acc + proj_b[label]);
            float mask = (label > 0) ? 1.f : 0.f;
            num += mask * nll;
            den += mask;
        }
    }
    if (lane == 0) atomicAdd(out, (num / (den + 1e-6f)) * (1.f / 64.f));
}

// ---------------------------------------------------------------------------
extern "C" void kernel_launch(void* const* d_in, const int* in_sizes, int n_in,
                              void* d_out, int out_size, void* d_ws, size_t ws_size,
                              hipStream_t stream) {
    const float* enc_h     = (const float*)d_in[0];
    const float* enc_out   = (const float*)d_in[1];
    const int*   seq_label = (const int*)d_in[3];
    const int*   dec_in    = (const int*)d_in[4];
    const float* style     = (const float*)d_in[5];
    const float* W_e2d_w   = (const float*)d_in[6];
    const float* W_e2d_b   = (const float*)d_in[7];
    const float* attn_W    = (const float*)d_in[8];
    const float* emb_table = (const float*)d_in[9];
    const float* w_ih      = (const float*)d_in[10];
    const float* w_hh      = (const float*)d_in[11];
    const float* b_ih      = (const float*)d_in[12];
    const float* b_hh      = (const float*)d_in[13];
    const float* proj_w    = (const float*)d_in[14];
    const float* proj_b    = (const float*)d_in[15];
    float* out = (float*)d_out;

    char* p = (char*)d_ws;
    float* partial = (float*)p;                    p += 500 * 1344 * 4;
    float* sumexp  = (float*)p;                    p += 1344 * 4 + 64;
    float* geT     = (float*)p;                    p += (size_t)21 * 2048 * 64 * 4;
    unsigned short* M_bf  = (unsigned short*)p;    p += (size_t)4096 * 512 * 2;
    unsigned short* wc2   = (unsigned short*)p;    p += (size_t)2048 * 1024 * 2;
    unsigned short* hseqb = (unsigned short*)p;    p += (size_t)1344 * 512 * 2;
    unsigned short* hb0   = (unsigned short*)p;    p += 64 * 512 * 2;
    unsigned short* hb1   = (unsigned short*)p;    p += 64 * 512 * 2;
    unsigned short* ctxb  = (unsigned short*)p;    p += 64 * 512 * 2;
    unsigned* bar = (unsigned*)p;                  p += 64 * 32 * 4;   // 64 flag lines

    hipMemsetAsync(out, 0, sizeof(float), stream);
    hipMemsetAsync(bar, 0, 64 * 32 * 4, stream);

    setup_kernel<<<3296, 256, 0, stream>>>(enc_h, style, W_e2d_w, W_e2d_b,
                                           enc_out, attn_W, w_ih, w_hh,
                                           emb_table, dec_in, b_ih, b_hh,
                                           hb0, wc2, M_bf, geT);

    {
        void* args[] = {(void*)&M_bf, (void*)&enc_out, (void*)&wc2, (void*)&geT,
                        (void*)&hb0, (void*)&hb1, (void*)&ctxb, (void*)&hseqb,
                        (void*)&bar};
        hipLaunchCooperativeKernel((const void*)scan_kernel, dim3(64),
                                   dim3(256), args, 0, stream);
    }

    proj_mfma_kernel<<<500, 256, 0, stream>>>(hseqb, proj_w, proj_b, partial);
    sumexp_reduce_kernel<<<42, 256, 0, stream>>>(partial, sumexp);
    loss_kernel<<<64, 64, 0, stream>>>(hseqb, proj_w, proj_b, sumexp, seq_label, out);
}

// Round 7
// 750.389 us; speedup vs baseline: 1.2765x; 1.0677x over previous
//
#include <hip/hip_runtime.h>
#include <hip/hip_bf16.h>
#include <math.h>

#define B 64
#define S 64
#define T 21
#define HID 512
#define VOCAB 32000

typedef __bf16 bf16x8 __attribute__((ext_vector_type(8)));
typedef float f32x4 __attribute__((ext_vector_type(4)));

union BF8 { unsigned short u[8]; bf16x8 v; uint4 q; };

__device__ __forceinline__ unsigned short f32_to_bf16_rne(float x) {
    union { float f; unsigned int u; } v;
    v.f = x;
    unsigned int u = v.u;
    unsigned int r = (u + 0x7FFFu + ((u >> 16) & 1u)) >> 16;
    return (unsigned short)r;
}

__device__ __forceinline__ float bf16_to_f32(unsigned short x) {
    union { unsigned int u; float f; } v;
    v.u = ((unsigned int)x) << 16;
    return v.f;
}

__device__ __forceinline__ bf16x8 cvt8(const float* p) {
    float4 f0 = *(const float4*)p;
    float4 f1 = *(const float4*)(p + 4);
    BF8 r;
    r.u[0] = f32_to_bf16_rne(f0.x); r.u[1] = f32_to_bf16_rne(f0.y);
    r.u[2] = f32_to_bf16_rne(f0.z); r.u[3] = f32_to_bf16_rne(f0.w);
    r.u[4] = f32_to_bf16_rne(f1.x); r.u[5] = f32_to_bf16_rne(f1.y);
    r.u[6] = f32_to_bf16_rne(f1.z); r.u[7] = f32_to_bf16_rne(f1.w);
    return r.v;
}

// ---------------------------------------------------------------------------
// Fused setup (unchanged). Block ranges:
//  [0,64)       h0 -> hb0 bf16
//  [64,2112)    wc2: [w_ih[:, :512] | w_hh] -> bf16 [n][1024]
//  [2112,2624)  mgemm: M[bs][j] = enc_out . attn_W  (bf16)
//  [2624,3296)  gegemm: geT[t][n][b] = emb(dec_in) . w_ih[:,512:].T + b_ih + b_hh
// ---------------------------------------------------------------------------
__global__ __launch_bounds__(256) void setup_kernel(
        const float* __restrict__ enc_h, const float* __restrict__ style,
        const float* __restrict__ W_e2d, const float* __restrict__ W_e2d_b,
        const float* __restrict__ enc_out, const float* __restrict__ attn_W,
        const float* __restrict__ w_ih, const float* __restrict__ w_hh,
        const float* __restrict__ emb_table, const int* __restrict__ dec_in,
        const float* __restrict__ b_ih, const float* __restrict__ b_hh,
        unsigned short* __restrict__ hb0, unsigned short* __restrict__ wc2,
        unsigned short* __restrict__ M_bf, float* __restrict__ geT) {
    int bid = blockIdx.x;
    int tid = threadIdx.x;
    __shared__ __attribute__((aligned(16))) float smem[640];

    if (bid < 64) {
        int b = bid;
        for (int i = tid; i < 512; i += 256) smem[i] = enc_h[b * 512 + i];
        if (tid < 128) smem[512 + tid] = style[b * 512 + 384 + tid];
        __syncthreads();
        for (int j = tid; j < 512; j += 256) {
            const float4* w4 = (const float4*)(W_e2d + (size_t)j * 640);
            float acc = 0.f;
#pragma unroll 4
            for (int k4 = 0; k4 < 160; k4++) {
                float4 w = w4[k4];
                float4 iv = *(const float4*)(smem + k4 * 4);
                acc += w.x * iv.x + w.y * iv.y + w.z * iv.z + w.w * iv.w;
            }
            hb0[b * 512 + j] = f32_to_bf16_rne(acc + W_e2d_b[j]);
        }
    } else if (bid < 2112) {
        int n = bid - 64;
        for (int k = tid; k < 1024; k += 256) {
            float v = (k < 512) ? w_ih[(size_t)n * 1024 + k]
                                : w_hh[(size_t)n * 512 + (k - 512)];
            wc2[(size_t)n * 1024 + k] = f32_to_bf16_rne(v);
        }
    } else if (bid < 2624) {
        int idx = bid - 2112;
        int xm = idx & 63, y = idx >> 6;
        int w = tid >> 6, lane = tid & 63;
        int col = lane & 15, kq = lane >> 4;
        int m0 = xm * 64 + w * 16;

        bf16x8 af[16];
        const float* arow = enc_out + (size_t)(m0 + col) * 512 + kq * 8;
#pragma unroll
        for (int ks = 0; ks < 16; ks++) af[ks] = cvt8(arow + ks * 32);

#pragma unroll
        for (int nt = 0; nt < 4; nt++) {
            int j0 = y * 64 + nt * 16;
            const float* brow = attn_W + (size_t)(j0 + col) * 512 + kq * 8;
            f32x4 acc = {0.f, 0.f, 0.f, 0.f};
#pragma unroll
            for (int ks = 0; ks < 16; ks++) {
                bf16x8 bf = cvt8(brow + ks * 32);
                acc = __builtin_amdgcn_mfma_f32_16x16x32_bf16(af[ks], bf, acc, 0, 0, 0);
            }
#pragma unroll
            for (int reg = 0; reg < 4; reg++) {
                int m = m0 + kq * 4 + reg;
                M_bf[(size_t)m * 512 + j0 + col] = f32_to_bf16_rne(acc[reg]);
            }
        }
    } else {
        int idx = bid - 2624;
        int mi = idx / 32, ni = idx - mi * 32;   // 21 m-tiles x 32 n-tiles
        int w = tid >> 6, lane = tid & 63;
        int col = lane & 15, kq = lane >> 4;
        int m0 = mi * 64 + w * 16;

        bf16x8 af[16];
        {
            int bt = m0 + col;
            int tok = dec_in[bt];
            const float* arow = emb_table + (size_t)tok * 512 + kq * 8;
#pragma unroll
            for (int ks = 0; ks < 16; ks++) af[ks] = cvt8(arow + ks * 32);
        }
#pragma unroll
        for (int nt = 0; nt < 4; nt++) {
            int n0 = ni * 64 + nt * 16;
            const float* brow = w_ih + (size_t)(n0 + col) * 1024 + 512 + kq * 8;
            f32x4 acc = {0.f, 0.f, 0.f, 0.f};
#pragma unroll
            for (int ks = 0; ks < 16; ks++) {
                bf16x8 bf = cvt8(brow + ks * 32);
                acc = __builtin_amdgcn_mfma_f32_16x16x32_bf16(af[ks], bf, acc, 0, 0, 0);
            }
#pragma unroll
            for (int reg = 0; reg < 4; reg++) {
                int m = m0 + kq * 4 + reg;      // bt index
                int n = n0 + col;
                int bb = m / T, tt = m - bb * T;
                geT[((size_t)tt * 2048 + n) * 64 + bb] = acc[reg] + b_ih[n] + b_hh[n];
            }
        }
    }
}

// ---------------------------------------------------------------------------
// Persistent scan (exact R2 form, 318 us known-good). Regular launch: the
// body uses only the hand-rolled flag barrier (no cooperative-groups API),
// and 64 blocks x ~140KB LDS (1 block/CU) on a 256-CU device are trivially
// co-resident, so a plain launch is legal. Isolates coop-launch overhead.
// ---------------------------------------------------------------------------
__global__ __launch_bounds__(256, 1) void scan_kernel(
        const unsigned short* __restrict__ M_bf,
        const float* __restrict__ enc_out,
        const unsigned short* __restrict__ wc2,
        const float* __restrict__ geT,
        unsigned short* __restrict__ hb0, unsigned short* __restrict__ hb1,
        unsigned short* __restrict__ ctxb, unsigned short* __restrict__ hseqb,
        unsigned* __restrict__ flags) {
    const int bk = blockIdx.x;
    const int tid = threadIdx.x;
    const int b = bk, u0 = bk * 8;
    const int lane = tid & 63, w = tid >> 6;
    const int col = lane & 15, kq = lane >> 4;

    __shared__ __attribute__((aligned(16))) unsigned short Mlds[64 * 512];
    __shared__ __attribute__((aligned(16))) unsigned short Wlds[32 * 1024];
    __shared__ __attribute__((aligned(16))) float fscr[2112];
    __shared__ float scp[4][64];
    __shared__ float hls[512];

    // Stage M[b] (swizzled: chunk' = c ^ (row&7))
#pragma unroll
    for (int i = 0; i < 16; i++) {
        int idx = i * 256 + tid;
        int r = idx >> 6, c = idx & 63;
        *(uint4*)(Mlds + r * 512 + ((c ^ (r & 7)) * 8)) =
            *(const uint4*)(M_bf + ((size_t)(b * 64 + r)) * 512 + c * 8);
    }
    // Stage W rows (swizzled)
#pragma unroll
    for (int i = 0; i < 16; i++) {
        int idx = i * 256 + tid;
        int r = idx >> 7, c = idx & 127;
        int gr = (r >> 3) * 512 + u0 + (r & 7);
        *(uint4*)(Wlds + r * 1024 + ((c ^ (r & 7)) * 8)) =
            *(const uint4*)(wc2 + (size_t)gr * 1024 + c * 8);
    }

    // In-register LSTM lane mapping: lane (col,kq) handles unit u0+(col&7),
    // batches b0+{0,1} (col<8) or b0+{2,3} (col>=8).
    float creg0 = 0.f, creg1 = 0.f;
    const int uloc = col & 7;
    const bool r01 = (col < 8);
    const int b0 = w * 16 + kq * 4;
    __syncthreads();

    unsigned bcnt = 0;
    for (int t = 0; t < T; t++) {
        unsigned short* hcur = (t & 1) ? hb1 : hb0;
        unsigned short* hnxt = (t & 1) ? hb0 : hb1;

        // ---- step-start loads: hls (critical) + phase-3 prefetches ----
        unsigned hw = *((const unsigned*)hcur + b * 256 + tid);
        uint4 hfr[16];
        {
            const unsigned short* arow_h = hcur + (size_t)(w * 16 + col) * 512 + kq * 8;
#pragma unroll
            for (int j = 0; j < 16; j++) hfr[j] = *(const uint4*)(arow_h + j * 32);
        }
        const float* ge = geT + (size_t)t * 2048 * 64;
        const int gA = r01 ? 0 : 1, gB = r01 ? 2 : 3;
        float4 geA4 = *(const float4*)(ge + (size_t)(gA * 512 + u0 + uloc) * 64 + b0);
        float4 geB4 = *(const float4*)(ge + (size_t)(gB * 512 + u0 + uloc) * 64 + b0);
        hls[2 * tid]     = bf16_to_f32((unsigned short)(hw & 0xffffu));
        hls[2 * tid + 1] = bf16_to_f32((unsigned short)(hw >> 16));
        __syncthreads();

        // ---------------- phase 1: attention for batch b ----------------
        {   // scores: s = lane, q = w covers d-range q*128..+128
            float acc = 0.f;
#pragma unroll
            for (int i = 0; i < 16; i++) {
                int c = w * 16 + i;
                BF8 mp;
                mp.q = *(const uint4*)(Mlds + lane * 512 + ((c ^ (lane & 7)) * 8));
                const float* hq = hls + w * 128 + i * 8;
#pragma unroll
                for (int j = 0; j < 8; j++) acc += bf16_to_f32(mp.u[j]) * hq[j];
            }
            scp[w][lane] = acc;
        }
        __syncthreads();
        // redundant per-wave softmax (identical ops/results in every wave)
        float a_l;
        {
            float v = scp[0][lane] + scp[1][lane] + scp[2][lane] + scp[3][lane];
            float m = v;
            for (int off = 32; off > 0; off >>= 1) m = fmaxf(m, __shfl_xor(m, off, 64));
            float e = __expf(v - m);
            float ss = e;
            for (int off = 32; off > 0; off >>= 1) ss += __shfl_xor(ss, off, 64);
            a_l = e / ss;
        }
        {   // ctx partials: w covers s-range, lane covers d = lane*8..+8
            float cp[8] = {0, 0, 0, 0, 0, 0, 0, 0};
#pragma unroll 4
            for (int si = 0; si < 16; si++) {
                int s = w * 16 + si;
                float a = __shfl(a_l, s, 64);
                const float* ep = enc_out + ((size_t)(b * 64 + s)) * 512 + lane * 8;
                float4 e0 = *(const float4*)ep;
                float4 e1 = *(const float4*)(ep + 4);
                cp[0] += a * e0.x; cp[1] += a * e0.y; cp[2] += a * e0.z; cp[3] += a * e0.w;
                cp[4] += a * e1.x; cp[5] += a * e1.y; cp[6] += a * e1.z; cp[7] += a * e1.w;
            }
            // lane-major, stride 66: conflict-free writes and reads
#pragma unroll
            for (int j = 0; j < 8; j++) fscr[w * 528 + j * 66 + lane] = cp[j];
        }
        __syncthreads();
        {   // reduce 4 partials, write ctx (bf16, packed u32 stores)
            int l0 = tid >> 2, j0 = (2 * tid) & 7;
            float v0 = fscr[j0 * 66 + l0] + fscr[528 + j0 * 66 + l0] +
                       fscr[1056 + j0 * 66 + l0] + fscr[1584 + j0 * 66 + l0];
            float v1 = fscr[(j0 + 1) * 66 + l0] + fscr[528 + (j0 + 1) * 66 + l0] +
                       fscr[1056 + (j0 + 1) * 66 + l0] + fscr[1584 + (j0 + 1) * 66 + l0];
            unsigned pack = (unsigned)f32_to_bf16_rne(v0) |
                            ((unsigned)f32_to_bf16_rne(v1) << 16);
            *(unsigned*)(ctxb + b * 512 + tid * 2) = pack;
        }

        // ---- barrier 1: arrive (own flag line), per-wave partial wait ----
        bcnt++;
        __syncthreads();
        if (tid == 0)
            __hip_atomic_store(&flags[bk * 32], bcnt, __ATOMIC_RELEASE,
                               __HIP_MEMORY_SCOPE_AGENT);
        if (kq == 0) {   // lanes 0..15 of each wave poll its 16 producers
            const unsigned* f = &flags[(w * 16 + col) * 32];
            while (__hip_atomic_load(f, __ATOMIC_RELAXED, __HIP_MEMORY_SCOPE_AGENT) < bcnt)
                __builtin_amdgcn_s_sleep(2);
        }
        __builtin_amdgcn_fence(__ATOMIC_ACQUIRE, "agent");

        // ---------------- phase 3: gates MFMA + in-register LSTM ----------------
        f32x4 acc0 = {0.f, 0.f, 0.f, 0.f};
        f32x4 acc1 = {0.f, 0.f, 0.f, 0.f};
        {
            uint4 cfr[16];
            const unsigned short* arow_c = ctxb + (size_t)(w * 16 + col) * 512 + kq * 8;
#pragma unroll
            for (int j = 0; j < 16; j++) cfr[j] = *(const uint4*)(arow_c + j * 32);

            int sw0 = col & 7;
            // h-part first: register operands, overlaps the cfr load latency
#pragma unroll
            for (int ks = 16; ks < 32; ks++) {
                BF8 a8; a8.q = hfr[ks - 16];
                int c = kq + 4 * ks;
                bf16x8 bf0 = *reinterpret_cast<const bf16x8*>(
                    Wlds + col * 1024 + ((c ^ sw0) * 8));
                bf16x8 bf1 = *reinterpret_cast<const bf16x8*>(
                    Wlds + (16 + col) * 1024 + ((c ^ sw0) * 8));
                acc0 = __builtin_amdgcn_mfma_f32_16x16x32_bf16(a8.v, bf0, acc0, 0, 0, 0);
                acc1 = __builtin_amdgcn_mfma_f32_16x16x32_bf16(a8.v, bf1, acc1, 0, 0, 0);
            }
#pragma unroll
            for (int ks = 0; ks < 16; ks++) {
                BF8 a8; a8.q = cfr[ks];
                int c = kq + 4 * ks;
                bf16x8 bf0 = *reinterpret_cast<const bf16x8*>(
                    Wlds + col * 1024 + ((c ^ sw0) * 8));
                bf16x8 bf1 = *reinterpret_cast<const bf16x8*>(
                    Wlds + (16 + col) * 1024 + ((c ^ sw0) * 8));
                acc0 = __builtin_amdgcn_mfma_f32_16x16x32_bf16(a8.v, bf0, acc0, 0, 0, 0);
                acc1 = __builtin_amdgcn_mfma_f32_16x16x32_bf16(a8.v, bf1, acc1, 0, 0, 0);
            }
        }
        {   // gates: D row (kq*4+reg)=batch, col<8 -> gate0/2 unit col,
            // col>=8 -> gate1/3 unit col-8. Exchange with partner lane^8.
            float go0[4], go1[4];
            float geAv[4] = {geA4.x, geA4.y, geA4.z, geA4.w};
            float geBv[4] = {geB4.x, geB4.y, geB4.z, geB4.w};
#pragma unroll
            for (int rg = 0; rg < 4; rg++) {
                go0[rg] = acc0[rg] + geAv[rg];
                go1[rg] = acc1[rg] + geBv[rg];
            }
            float sh0 = __shfl_xor(r01 ? go0[2] : go0[0], 8, 64);
            float sh1 = __shfl_xor(r01 ? go0[3] : go0[1], 8, 64);
            float sh2 = __shfl_xor(r01 ? go1[2] : go1[0], 8, 64);
            float sh3 = __shfl_xor(r01 ? go1[3] : go1[1], 8, 64);
            int u = u0 + uloc;
            int bA = b0 + (r01 ? 0 : 2);
            {
                float G0 = r01 ? go0[0] : sh0;
                float G1 = r01 ? sh0 : go0[2];
                float G2 = r01 ? go1[0] : sh2;
                float G3 = r01 ? sh2 : go1[2];
                float ig = 1.f / (1.f + __expf(-G0));
                float fg = 1.f / (1.f + __expf(-G1));
                float gt = tanhf(G2);
                float og = 1.f / (1.f + __expf(-G3));
                creg0 = fg * creg0 + ig * gt;
                float hn = og * tanhf(creg0);
                unsigned short hv = f32_to_bf16_rne(hn);
                hnxt[bA * 512 + u] = hv;
                hseqb[((size_t)bA * T + t) * 512 + u] = hv;
            }
            {
                float G0 = r01 ? go0[1] : sh1;
                float G1 = r01 ? sh1 : go0[3];
                float G2 = r01 ? go1[1] : sh3;
                float G3 = r01 ? sh3 : go1[3];
                float ig = 1.f / (1.f + __expf(-G0));
                float fg = 1.f / (1.f + __expf(-G1));
                float gt = tanhf(G2);
                float og = 1.f / (1.f + __expf(-G3));
                creg1 = fg * creg1 + ig * gt;
                float hn = og * tanhf(creg1);
                unsigned short hv = f32_to_bf16_rne(hn);
                int bB = bA + 1;
                hnxt[bB * 512 + u] = hv;
                hseqb[((size_t)bB * T + t) * 512 + u] = hv;
            }
        }

        // ---- barrier 2: full (h is all-to-all); skip after last step ----
        bcnt++;
        if (t < T - 1) {
            __syncthreads();
            if (tid == 0)
                __hip_atomic_store(&flags[bk * 32], bcnt, __ATOMIC_RELEASE,
                                   __HIP_MEMORY_SCOPE_AGENT);
            if (tid < 64) {
                const unsigned* f = &flags[tid * 32];
                while (__hip_atomic_load(f, __ATOMIC_RELAXED, __HIP_MEMORY_SCOPE_AGENT) < bcnt)
                    __builtin_amdgcn_s_sleep(2);
            }
            __builtin_amdgcn_fence(__ATOMIC_ACQUIRE, "agent");
            __syncthreads();
        }
    }
}

// ---------------------------------------------------------------------------
// Projection + exp-sum (known-good single-buffer form).
// grid(500), block(256). Wave wv: nhalf = wv&1, mhalf = wv>>1. hseq tile in
// XOR-swizzled LDS; 1 ds_read feeds 2 MFMAs. Epilogue: 8 exps -> one LDS
// atomicAdd per lane per tile.
// ---------------------------------------------------------------------------
__global__ __launch_bounds__(256) void proj_mfma_kernel(
        const unsigned short* __restrict__ hseqb,
        const float* __restrict__ proj_w,
        const float* __restrict__ proj_b,
        float* __restrict__ partial) {
    int tid = threadIdx.x;
    int wv = tid >> 6, lane = tid & 63;
    int col = lane & 15, kq = lane >> 4;
    int nhalf = wv & 1, mhalf = wv >> 1;
    int n0 = blockIdx.x * 64 + nhalf * 32;

    bf16x8 Af0[16], Af1[16];
    {
        const float* w0 = proj_w + (size_t)(n0 + col) * 512 + kq * 8;
        const float* w1 = proj_w + (size_t)(n0 + 16 + col) * 512 + kq * 8;
#pragma unroll
        for (int ks = 0; ks < 16; ks++) {
            Af0[ks] = cvt8(w0 + ks * 32);
            Af1[ks] = cvt8(w1 + ks * 32);
        }
    }
    float4 bias0 = *(const float4*)(proj_b + n0 + kq * 4);
    float4 bias1 = *(const float4*)(proj_b + n0 + 16 + kq * 4);

    __shared__ __attribute__((aligned(16))) unsigned short alds[32 * 512];
    __shared__ float esum[1344];
    for (int i = tid; i < 1344; i += 256) esum[i] = 0.f;
    __syncthreads();

    for (int mt = 0; mt < 42; mt++) {
        int mA = mt * 32;
        __syncthreads();
#pragma unroll
        for (int i = 0; i < 8; i++) {
            int idx = i * 256 + tid;
            int r = idx >> 6, c = idx & 63;
            *(uint4*)(alds + r * 512 + ((c ^ (r & 7)) * 8)) =
                *(const uint4*)(hseqb + (size_t)(mA + r) * 512 + c * 8);
        }
        __syncthreads();
        int rr = mhalf * 16 + col;
        int sw = rr & 7;
        f32x4 acc0 = {0.f, 0.f, 0.f, 0.f};
        f32x4 acc1 = {0.f, 0.f, 0.f, 0.f};
#pragma unroll
        for (int ks = 0; ks < 16; ks++) {
            int c = kq + 4 * ks;
            bf16x8 bf = *reinterpret_cast<const bf16x8*>(
                alds + rr * 512 + ((c ^ sw) * 8));
            acc0 = __builtin_amdgcn_mfma_f32_16x16x32_bf16(Af0[ks], bf, acc0, 0, 0, 0);
            acc1 = __builtin_amdgcn_mfma_f32_16x16x32_bf16(Af1[ks], bf, acc1, 0, 0, 0);
        }
        float e = __expf(acc0[0] + bias0.x) + __expf(acc0[1] + bias0.y) +
                  __expf(acc0[2] + bias0.z) + __expf(acc0[3] + bias0.w) +
                  __expf(acc1[0] + bias1.x) + __expf(acc1[1] + bias1.y) +
                  __expf(acc1[2] + bias1.z) + __expf(acc1[3] + bias1.w);
        atomicAdd(&esum[mA + rr], e);
    }
    __syncthreads();
    for (int i = tid; i < 1344; i += 256)
        partial[(size_t)blockIdx.x * 1344 + i] = esum[i];
}

// ---------------------------------------------------------------------------
__global__ __launch_bounds__(256) void sumexp_reduce_kernel(
        const float* __restrict__ partial, float* __restrict__ sumexp) {
    int m = blockIdx.x * 32 + (threadIdx.x >> 3);
    int sub = threadIdx.x & 7;
    float s = 0.f;
    for (int nb = sub; nb < 500; nb += 8) s += partial[(size_t)nb * 1344 + m];
    s += __shfl_xor(s, 1, 64);
    s += __shfl_xor(s, 2, 64);
    s += __shfl_xor(s, 4, 64);
    if (sub == 0) sumexp[m] = s;
}

// ---------------------------------------------------------------------------
__global__ __launch_bounds__(64) void loss_kernel(
        const unsigned short* __restrict__ hseqb,
        const float* __restrict__ proj_w, const float* __restrict__ proj_b,
        const float* __restrict__ sumexp, const int* __restrict__ seq_label,
        float* __restrict__ out) {
    int b = blockIdx.x;
    int lane = threadIdx.x;
    float num = 0.f, den = 0.f;
    for (int t = 0; t < T; t++) {
        int label = seq_label[b * T + t];
        const unsigned short* hp = hseqb + ((size_t)b * T + t) * 512;
        const float* wp = proj_w + (size_t)label * 512;
        float acc = 0.f;
#pragma unroll
        for (int i = 0; i < 8; i++)
            acc += bf16_to_f32(hp[lane + 64 * i]) * wp[lane + 64 * i];
        for (int off = 32; off > 0; off >>= 1) acc += __shfl_xor(acc, off, 64);
        if (lane == 0) {
            float nll = logf(sumexp[b * T + t]) - (acc + proj_b[label]);
            float mask = (label > 0) ? 1.f : 0.f;
            num += mask * nll;
            den += mask;
        }
    }
    if (lane == 0) atomicAdd(out, (num / (den + 1e-6f)) * (1.f / 64.f));
}

// ---------------------------------------------------------------------------
extern "C" void kernel_launch(void* const* d_in, const int* in_sizes, int n_in,
                              void* d_out, int out_size, void* d_ws, size_t ws_size,
                              hipStream_t stream) {
    const float* enc_h     = (const float*)d_in[0];
    const float* enc_out   = (const float*)d_in[1];
    const int*   seq_label = (const int*)d_in[3];
    const int*   dec_in    = (const int*)d_in[4];
    const float* style     = (const float*)d_in[5];
    const float* W_e2d_w   = (const float*)d_in[6];
    const float* W_e2d_b   = (const float*)d_in[7];
    const float* attn_W    = (const float*)d_in[8];
    const float* emb_table = (const float*)d_in[9];
    const float* w_ih      = (const float*)d_in[10];
    const float* w_hh      = (const float*)d_in[11];
    const float* b_ih      = (const float*)d_in[12];
    const float* b_hh      = (const float*)d_in[13];
    const float* proj_w    = (const float*)d_in[14];
    const float* proj_b    = (const float*)d_in[15];
    float* out = (float*)d_out;

    char* p = (char*)d_ws;
    float* partial = (float*)p;                    p += 500 * 1344 * 4;
    float* sumexp  = (float*)p;                    p += 1344 * 4 + 64;
    float* geT     = (float*)p;                    p += (size_t)21 * 2048 * 64 * 4;
    unsigned short* M_bf  = (unsigned short*)p;    p += (size_t)4096 * 512 * 2;
    unsigned short* wc2   = (unsigned short*)p;    p += (size_t)2048 * 1024 * 2;
    unsigned short* hseqb = (unsigned short*)p;    p += (size_t)1344 * 512 * 2;
    unsigned short* hb0   = (unsigned short*)p;    p += 64 * 512 * 2;
    unsigned short* hb1   = (unsigned short*)p;    p += 64 * 512 * 2;
    unsigned short* ctxb  = (unsigned short*)p;    p += 64 * 512 * 2;
    unsigned* bar = (unsigned*)p;                  p += 64 * 32 * 4;   // 64 flag lines

    hipMemsetAsync(out, 0, sizeof(float), stream);
    hipMemsetAsync(bar, 0, 64 * 32 * 4, stream);

    setup_kernel<<<3296, 256, 0, stream>>>(enc_h, style, W_e2d_w, W_e2d_b,
                                           enc_out, attn_W, w_ih, w_hh,
                                           emb_table, dec_in, b_ih, b_hh,
                                           hb0, wc2, M_bf, geT);

    // Regular launch (was hipLaunchCooperativeKernel): 64 blocks, 1/CU by
    // LDS, guaranteed co-resident on 256 CUs; kernel uses only hand-rolled
    // flag barriers. Isolates coop-launch overhead as this round's variable.
    scan_kernel<<<64, 256, 0, stream>>>(M_bf, enc_out, wc2, geT,
                                        hb0, hb1, ctxb, hseqb, bar);

    proj_mfma_kernel<<<500, 256, 0, stream>>>(hseqb, proj_w, proj_b, partial);
    sumexp_reduce_kernel<<<42, 256, 0, stream>>>(partial, sumexp);
    loss_kernel<<<64, 64, 0, stream>>>(hseqb, proj_w, proj_b, sumexp, seq_label, out);
}

// Round 8
// 661.454 us; speedup vs baseline: 1.4481x; 1.1345x over previous
//
#include <hip/hip_runtime.h>
#include <hip/hip_bf16.h>
#include <math.h>

#define B 64
#define S 64
#define T 21
#define HID 512
#define VOCAB 32000

typedef __bf16 bf16x8 __attribute__((ext_vector_type(8)));
typedef float f32x4 __attribute__((ext_vector_type(4)));

union BF8 { unsigned short u[8]; bf16x8 v; uint4 q; };

__device__ __forceinline__ unsigned short f32_to_bf16_rne(float x) {
    union { float f; unsigned int u; } v;
    v.f = x;
    unsigned int u = v.u;
    unsigned int r = (u + 0x7FFFu + ((u >> 16) & 1u)) >> 16;
    return (unsigned short)r;
}

__device__ __forceinline__ float bf16_to_f32(unsigned short x) {
    union { unsigned int u; float f; } v;
    v.u = ((unsigned int)x) << 16;
    return v.f;
}

__device__ __forceinline__ bf16x8 cvt8(const float* p) {
    float4 f0 = *(const float4*)p;
    float4 f1 = *(const float4*)(p + 4);
    BF8 r;
    r.u[0] = f32_to_bf16_rne(f0.x); r.u[1] = f32_to_bf16_rne(f0.y);
    r.u[2] = f32_to_bf16_rne(f0.z); r.u[3] = f32_to_bf16_rne(f0.w);
    r.u[4] = f32_to_bf16_rne(f1.x); r.u[5] = f32_to_bf16_rne(f1.y);
    r.u[6] = f32_to_bf16_rne(f1.z); r.u[7] = f32_to_bf16_rne(f1.w);
    return r.v;
}

// --- Coherent (L1/L2-bypass, IF-coherent) access helpers -------------------
// Wide vector ops with sc0 sc1 scope bits: coalesced 16B/lane (R4 lesson:
// never per-lane 4B atomics for bulk data). No acquire/release fences are
// used anywhere in the scan -> no buffer_wbl2 / buffer_inv L2 walks.
__device__ __forceinline__ void ldg_coh_x4(uint4* r, const void* p) {
    asm volatile("global_load_dwordx4 %0, %1, off sc0 sc1"
                 : "=v"(*r) : "v"(p) : "memory");
}
__device__ __forceinline__ void ldg_coh_u32(unsigned* r, const void* p) {
    asm volatile("global_load_dword %0, %1, off sc0 sc1"
                 : "=v"(*r) : "v"(p) : "memory");
}
__device__ __forceinline__ void stg_coh_u32(void* p, unsigned v) {
    asm volatile("global_store_dword %0, %1, off sc0 sc1"
                 :: "v"(p), "v"(v) : "memory");
}
__device__ __forceinline__ void stg_coh_u16(void* p, unsigned v) {
    asm volatile("global_store_short %0, %1, off sc0 sc1"
                 :: "v"(p), "v"(v) : "memory");
}
// Drain all outstanding vector-memory ops; sched_barrier stops the compiler
// from hoisting dependent code above the wait (rule #18).
__device__ __forceinline__ void wait_vm0() {
    asm volatile("s_waitcnt vmcnt(0)" ::: "memory");
    __builtin_amdgcn_sched_barrier(0);
}

// ---------------------------------------------------------------------------
// Fused setup (unchanged). Block ranges:
//  [0,64)       h0 -> hb0 bf16
//  [64,2112)    wc2: [w_ih[:, :512] | w_hh] -> bf16 [n][1024]
//  [2112,2624)  mgemm: M[bs][j] = enc_out . attn_W  (bf16)
//  [2624,3296)  gegemm: geT[t][n][b] = emb(dec_in) . w_ih[:,512:].T + b_ih + b_hh
// ---------------------------------------------------------------------------
__global__ __launch_bounds__(256) void setup_kernel(
        const float* __restrict__ enc_h, const float* __restrict__ style,
        const float* __restrict__ W_e2d, const float* __restrict__ W_e2d_b,
        const float* __restrict__ enc_out, const float* __restrict__ attn_W,
        const float* __restrict__ w_ih, const float* __restrict__ w_hh,
        const float* __restrict__ emb_table, const int* __restrict__ dec_in,
        const float* __restrict__ b_ih, const float* __restrict__ b_hh,
        unsigned short* __restrict__ hb0, unsigned short* __restrict__ wc2,
        unsigned short* __restrict__ M_bf, float* __restrict__ geT) {
    int bid = blockIdx.x;
    int tid = threadIdx.x;
    __shared__ __attribute__((aligned(16))) float smem[640];

    if (bid < 64) {
        int b = bid;
        for (int i = tid; i < 512; i += 256) smem[i] = enc_h[b * 512 + i];
        if (tid < 128) smem[512 + tid] = style[b * 512 + 384 + tid];
        __syncthreads();
        for (int j = tid; j < 512; j += 256) {
            const float4* w4 = (const float4*)(W_e2d + (size_t)j * 640);
            float acc = 0.f;
#pragma unroll 4
            for (int k4 = 0; k4 < 160; k4++) {
                float4 w = w4[k4];
                float4 iv = *(const float4*)(smem + k4 * 4);
                acc += w.x * iv.x + w.y * iv.y + w.z * iv.z + w.w * iv.w;
            }
            hb0[b * 512 + j] = f32_to_bf16_rne(acc + W_e2d_b[j]);
        }
    } else if (bid < 2112) {
        int n = bid - 64;
        for (int k = tid; k < 1024; k += 256) {
            float v = (k < 512) ? w_ih[(size_t)n * 1024 + k]
                                : w_hh[(size_t)n * 512 + (k - 512)];
            wc2[(size_t)n * 1024 + k] = f32_to_bf16_rne(v);
        }
    } else if (bid < 2624) {
        int idx = bid - 2112;
        int xm = idx & 63, y = idx >> 6;
        int w = tid >> 6, lane = tid & 63;
        int col = lane & 15, kq = lane >> 4;
        int m0 = xm * 64 + w * 16;

        bf16x8 af[16];
        const float* arow = enc_out + (size_t)(m0 + col) * 512 + kq * 8;
#pragma unroll
        for (int ks = 0; ks < 16; ks++) af[ks] = cvt8(arow + ks * 32);

#pragma unroll
        for (int nt = 0; nt < 4; nt++) {
            int j0 = y * 64 + nt * 16;
            const float* brow = attn_W + (size_t)(j0 + col) * 512 + kq * 8;
            f32x4 acc = {0.f, 0.f, 0.f, 0.f};
#pragma unroll
            for (int ks = 0; ks < 16; ks++) {
                bf16x8 bf = cvt8(brow + ks * 32);
                acc = __builtin_amdgcn_mfma_f32_16x16x32_bf16(af[ks], bf, acc, 0, 0, 0);
            }
#pragma unroll
            for (int reg = 0; reg < 4; reg++) {
                int m = m0 + kq * 4 + reg;
                M_bf[(size_t)m * 512 + j0 + col] = f32_to_bf16_rne(acc[reg]);
            }
        }
    } else {
        int idx = bid - 2624;
        int mi = idx / 32, ni = idx - mi * 32;   // 21 m-tiles x 32 n-tiles
        int w = tid >> 6, lane = tid & 63;
        int col = lane & 15, kq = lane >> 4;
        int m0 = mi * 64 + w * 16;

        bf16x8 af[16];
        {
            int bt = m0 + col;
            int tok = dec_in[bt];
            const float* arow = emb_table + (size_t)tok * 512 + kq * 8;
#pragma unroll
            for (int ks = 0; ks < 16; ks++) af[ks] = cvt8(arow + ks * 32);
        }
#pragma unroll
        for (int nt = 0; nt < 4; nt++) {
            int n0 = ni * 64 + nt * 16;
            const float* brow = w_ih + (size_t)(n0 + col) * 1024 + 512 + kq * 8;
            f32x4 acc = {0.f, 0.f, 0.f, 0.f};
#pragma unroll
            for (int ks = 0; ks < 16; ks++) {
                bf16x8 bf = cvt8(brow + ks * 32);
                acc = __builtin_amdgcn_mfma_f32_16x16x32_bf16(af[ks], bf, acc, 0, 0, 0);
            }
#pragma unroll
            for (int reg = 0; reg < 4; reg++) {
                int m = m0 + kq * 4 + reg;      // bt index
                int n = n0 + col;
                int bb = m / T, tt = m - bb * T;
                geT[((size_t)tt * 2048 + n) * 64 + bb] = acc[reg] + b_ih[n] + b_hh[n];
            }
        }
    }
}

// ---------------------------------------------------------------------------
// Persistent scan: regular launch (R7-proven), FENCE-FREE sync protocol.
// The exchanged data (ctxb, hb) moves through the coherence point (IF)
// directly via sc0sc1 write-through stores / L2-bypass wide loads:
//   producer: sc0sc1 stores -> s_waitcnt vmcnt(0) -> __syncthreads ->
//             RELAXED agent flag store (no release => no buffer_wbl2 walk)
//   consumer: flag poll -> sc0sc1 dwordx4 loads (no acquire => no buffer_inv)
// Since hb/ctxb are never accessed through L1/L2, no stale copies can exist.
// Side win: enc_out/M/W/geT stay L1/L2-warm for all 21 steps (no more
// per-step invalidation). Barrier graph (bar1 partial, bar2 full, monotone
// counters) identical to the proven R2 kernel.
// ---------------------------------------------------------------------------
__global__ __launch_bounds__(256, 1) void scan_kernel(
        const unsigned short* __restrict__ M_bf,
        const float* __restrict__ enc_out,
        const unsigned short* __restrict__ wc2,
        const float* __restrict__ geT,
        unsigned short* __restrict__ hb0, unsigned short* __restrict__ hb1,
        unsigned short* __restrict__ ctxb, unsigned short* __restrict__ hseqb,
        unsigned* __restrict__ flags) {
    const int bk = blockIdx.x;
    const int tid = threadIdx.x;
    const int b = bk, u0 = bk * 8;
    const int lane = tid & 63, w = tid >> 6;
    const int col = lane & 15, kq = lane >> 4;

    __shared__ __attribute__((aligned(16))) unsigned short Mlds[64 * 512];
    __shared__ __attribute__((aligned(16))) unsigned short Wlds[32 * 1024];
    __shared__ __attribute__((aligned(16))) float fscr[2112];
    __shared__ float scp[4][64];
    __shared__ float hls[512];

    // Stage M[b] (swizzled: chunk' = c ^ (row&7))
#pragma unroll
    for (int i = 0; i < 16; i++) {
        int idx = i * 256 + tid;
        int r = idx >> 6, c = idx & 63;
        *(uint4*)(Mlds + r * 512 + ((c ^ (r & 7)) * 8)) =
            *(const uint4*)(M_bf + ((size_t)(b * 64 + r)) * 512 + c * 8);
    }
    // Stage W rows (swizzled)
#pragma unroll
    for (int i = 0; i < 16; i++) {
        int idx = i * 256 + tid;
        int r = idx >> 7, c = idx & 127;
        int gr = (r >> 3) * 512 + u0 + (r & 7);
        *(uint4*)(Wlds + r * 1024 + ((c ^ (r & 7)) * 8)) =
            *(const uint4*)(wc2 + (size_t)gr * 1024 + c * 8);
    }

    // In-register LSTM lane mapping: lane (col,kq) handles unit u0+(col&7),
    // batches b0+{0,1} (col<8) or b0+{2,3} (col>=8).
    float creg0 = 0.f, creg1 = 0.f;
    const int uloc = col & 7;
    const bool r01 = (col < 8);
    const int b0 = w * 16 + kq * 4;
    __syncthreads();

    unsigned bcnt = 0;
    for (int t = 0; t < T; t++) {
        unsigned short* hcur = (t & 1) ? hb1 : hb0;
        unsigned short* hnxt = (t & 1) ? hb0 : hb1;

        // ---- step-start loads: hb is remote-written -> coherent loads ----
        unsigned hw;
        ldg_coh_u32(&hw, (const unsigned*)hcur + b * 256 + tid);
        uint4 hfr[16];
        {
            const unsigned short* arow_h = hcur + (size_t)(w * 16 + col) * 512 + kq * 8;
#pragma unroll
            for (int j = 0; j < 16; j++) ldg_coh_x4(&hfr[j], arow_h + j * 32);
        }
        const float* ge = geT + (size_t)t * 2048 * 64;   // L2-warm (no invs)
        const int gA = r01 ? 0 : 1, gB = r01 ? 2 : 3;
        float4 geA4 = *(const float4*)(ge + (size_t)(gA * 512 + u0 + uloc) * 64 + b0);
        float4 geB4 = *(const float4*)(ge + (size_t)(gB * 512 + u0 + uloc) * 64 + b0);
        wait_vm0();
        hls[2 * tid]     = bf16_to_f32((unsigned short)(hw & 0xffffu));
        hls[2 * tid + 1] = bf16_to_f32((unsigned short)(hw >> 16));
        __syncthreads();

        // ---------------- phase 1: attention for batch b ----------------
        {   // scores: s = lane, q = w covers d-range q*128..+128
            float acc = 0.f;
#pragma unroll
            for (int i = 0; i < 16; i++) {
                int c = w * 16 + i;
                BF8 mp;
                mp.q = *(const uint4*)(Mlds + lane * 512 + ((c ^ (lane & 7)) * 8));
                const float* hq = hls + w * 128 + i * 8;
#pragma unroll
                for (int j = 0; j < 8; j++) acc += bf16_to_f32(mp.u[j]) * hq[j];
            }
            scp[w][lane] = acc;
        }
        __syncthreads();
        // redundant per-wave softmax (identical ops/results in every wave)
        float a_l;
        {
            float v = scp[0][lane] + scp[1][lane] + scp[2][lane] + scp[3][lane];
            float m = v;
            for (int off = 32; off > 0; off >>= 1) m = fmaxf(m, __shfl_xor(m, off, 64));
            float e = __expf(v - m);
            float ss = e;
            for (int off = 32; off > 0; off >>= 1) ss += __shfl_xor(ss, off, 64);
            a_l = e / ss;
        }
        {   // ctx partials: w covers s-range, lane covers d = lane*8..+8
            float cp[8] = {0, 0, 0, 0, 0, 0, 0, 0};
#pragma unroll 4
            for (int si = 0; si < 16; si++) {
                int s = w * 16 + si;
                float a = __shfl(a_l, s, 64);
                const float* ep = enc_out + ((size_t)(b * 64 + s)) * 512 + lane * 8;
                float4 e0 = *(const float4*)ep;
                float4 e1 = *(const float4*)(ep + 4);
                cp[0] += a * e0.x; cp[1] += a * e0.y; cp[2] += a * e0.z; cp[3] += a * e0.w;
                cp[4] += a * e1.x; cp[5] += a * e1.y; cp[6] += a * e1.z; cp[7] += a * e1.w;
            }
            // lane-major, stride 66: conflict-free writes and reads
#pragma unroll
            for (int j = 0; j < 8; j++) fscr[w * 528 + j * 66 + lane] = cp[j];
        }
        __syncthreads();
        {   // reduce 4 partials, write ctx (coherent write-through store)
            int l0 = tid >> 2, j0 = (2 * tid) & 7;
            float v0 = fscr[j0 * 66 + l0] + fscr[528 + j0 * 66 + l0] +
                       fscr[1056 + j0 * 66 + l0] + fscr[1584 + j0 * 66 + l0];
            float v1 = fscr[(j0 + 1) * 66 + l0] + fscr[528 + (j0 + 1) * 66 + l0] +
                       fscr[1056 + (j0 + 1) * 66 + l0] + fscr[1584 + (j0 + 1) * 66 + l0];
            unsigned pack = (unsigned)f32_to_bf16_rne(v0) |
                            ((unsigned)f32_to_bf16_rne(v1) << 16);
            stg_coh_u32(ctxb + b * 512 + tid * 2, pack);
        }

        // ---- barrier 1: drain stores, arrive, per-wave partial wait ----
        bcnt++;
        wait_vm0();          // ctx stores acked at coherence point
        __syncthreads();     // all 256 threads' stores drained
        if (tid == 0)
            __hip_atomic_store(&flags[bk * 32], bcnt, __ATOMIC_RELAXED,
                               __HIP_MEMORY_SCOPE_AGENT);
        if (kq == 0) {   // lanes 0..15 of each wave poll its 16 producers
            const unsigned* f = &flags[(w * 16 + col) * 32];
            while (__hip_atomic_load(f, __ATOMIC_RELAXED, __HIP_MEMORY_SCOPE_AGENT) < bcnt)
                __builtin_amdgcn_s_sleep(2);
        }
        // no acquire fence: ctx read below bypasses L1/L2

        // ---------------- phase 3: gates MFMA + in-register LSTM ----------------
        f32x4 acc0 = {0.f, 0.f, 0.f, 0.f};
        f32x4 acc1 = {0.f, 0.f, 0.f, 0.f};
        {
            uint4 cfr[16];
            const unsigned short* arow_c = ctxb + (size_t)(w * 16 + col) * 512 + kq * 8;
#pragma unroll
            for (int j = 0; j < 16; j++) ldg_coh_x4(&cfr[j], arow_c + j * 32);

            int sw0 = col & 7;
            // h-part first (register operands): overlaps the cfr load latency
#pragma unroll
            for (int ks = 16; ks < 32; ks++) {
                BF8 a8; a8.q = hfr[ks - 16];
                int c = kq + 4 * ks;
                bf16x8 bf0 = *reinterpret_cast<const bf16x8*>(
                    Wlds + col * 1024 + ((c ^ sw0) * 8));
                bf16x8 bf1 = *reinterpret_cast<const bf16x8*>(
                    Wlds + (16 + col) * 1024 + ((c ^ sw0) * 8));
                acc0 = __builtin_amdgcn_mfma_f32_16x16x32_bf16(a8.v, bf0, acc0, 0, 0, 0);
                acc1 = __builtin_amdgcn_mfma_f32_16x16x32_bf16(a8.v, bf1, acc1, 0, 0, 0);
            }
            wait_vm0();      // cfr loads landed
#pragma unroll
            for (int ks = 0; ks < 16; ks++) {
                BF8 a8; a8.q = cfr[ks];
                int c = kq + 4 * ks;
                bf16x8 bf0 = *reinterpret_cast<const bf16x8*>(
                    Wlds + col * 1024 + ((c ^ sw0) * 8));
                bf16x8 bf1 = *reinterpret_cast<const bf16x8*>(
                    Wlds + (16 + col) * 1024 + ((c ^ sw0) * 8));
                acc0 = __builtin_amdgcn_mfma_f32_16x16x32_bf16(a8.v, bf0, acc0, 0, 0, 0);
                acc1 = __builtin_amdgcn_mfma_f32_16x16x32_bf16(a8.v, bf1, acc1, 0, 0, 0);
            }
        }
        {   // gates: D row (kq*4+reg)=batch, col<8 -> gate0/2 unit col,
            // col>=8 -> gate1/3 unit col-8. Exchange with partner lane^8.
            float go0[4], go1[4];
            float geAv[4] = {geA4.x, geA4.y, geA4.z, geA4.w};
            float geBv[4] = {geB4.x, geB4.y, geB4.z, geB4.w};
#pragma unroll
            for (int rg = 0; rg < 4; rg++) {
                go0[rg] = acc0[rg] + geAv[rg];
                go1[rg] = acc1[rg] + geBv[rg];
            }
            float sh0 = __shfl_xor(r01 ? go0[2] : go0[0], 8, 64);
            float sh1 = __shfl_xor(r01 ? go0[3] : go0[1], 8, 64);
            float sh2 = __shfl_xor(r01 ? go1[2] : go1[0], 8, 64);
            float sh3 = __shfl_xor(r01 ? go1[3] : go1[1], 8, 64);
            int u = u0 + uloc;
            int bA = b0 + (r01 ? 0 : 2);
            {
                float G0 = r01 ? go0[0] : sh0;
                float G1 = r01 ? sh0 : go0[2];
                float G2 = r01 ? go1[0] : sh2;
                float G3 = r01 ? sh2 : go1[2];
                float ig = 1.f / (1.f + __expf(-G0));
                float fg = 1.f / (1.f + __expf(-G1));
                float gt = tanhf(G2);
                float og = 1.f / (1.f + __expf(-G3));
                creg0 = fg * creg0 + ig * gt;
                float hn = og * tanhf(creg0);
                unsigned short hv = f32_to_bf16_rne(hn);
                stg_coh_u16(hnxt + bA * 512 + u, (unsigned)hv);   // remote-read next step
                hseqb[((size_t)bA * T + t) * 512 + u] = hv;       // kernel-boundary consumer
            }
            {
                float G0 = r01 ? go0[1] : sh1;
                float G1 = r01 ? sh1 : go0[3];
                float G2 = r01 ? go1[1] : sh3;
                float G3 = r01 ? sh3 : go1[3];
                float ig = 1.f / (1.f + __expf(-G0));
                float fg = 1.f / (1.f + __expf(-G1));
                float gt = tanhf(G2);
                float og = 1.f / (1.f + __expf(-G3));
                creg1 = fg * creg1 + ig * gt;
                float hn = og * tanhf(creg1);
                unsigned short hv = f32_to_bf16_rne(hn);
                int bB = bA + 1;
                stg_coh_u16(hnxt + bB * 512 + u, (unsigned)hv);
                hseqb[((size_t)bB * T + t) * 512 + u] = hv;
            }
        }

        // ---- barrier 2: full (h is all-to-all); skip after last step ----
        bcnt++;
        if (t < T - 1) {
            wait_vm0();      // h stores acked at coherence point
            __syncthreads();
            if (tid == 0)
                __hip_atomic_store(&flags[bk * 32], bcnt, __ATOMIC_RELAXED,
                                   __HIP_MEMORY_SCOPE_AGENT);
            if (tid < 64) {
                const unsigned* f = &flags[tid * 32];
                while (__hip_atomic_load(f, __ATOMIC_RELAXED, __HIP_MEMORY_SCOPE_AGENT) < bcnt)
                    __builtin_amdgcn_s_sleep(2);
            }
            // no acquire fence: next step's hb reads bypass L1/L2
            __syncthreads();
        }
    }
}

// ---------------------------------------------------------------------------
// Projection + exp-sum (known-good single-buffer form).
// grid(500), block(256). Wave wv: nhalf = wv&1, mhalf = wv>>1. hseq tile in
// XOR-swizzled LDS; 1 ds_read feeds 2 MFMAs. Epilogue: 8 exps -> one LDS
// atomicAdd per lane per tile.
// ---------------------------------------------------------------------------
__global__ __launch_bounds__(256) void proj_mfma_kernel(
        const unsigned short* __restrict__ hseqb,
        const float* __restrict__ proj_w,
        const float* __restrict__ proj_b,
        float* __restrict__ partial) {
    int tid = threadIdx.x;
    int wv = tid >> 6, lane = tid & 63;
    int col = lane & 15, kq = lane >> 4;
    int nhalf = wv & 1, mhalf = wv >> 1;
    int n0 = blockIdx.x * 64 + nhalf * 32;

    bf16x8 Af0[16], Af1[16];
    {
        const float* w0 = proj_w + (size_t)(n0 + col) * 512 + kq * 8;
        const float* w1 = proj_w + (size_t)(n0 + 16 + col) * 512 + kq * 8;
#pragma unroll
        for (int ks = 0; ks < 16; ks++) {
            Af0[ks] = cvt8(w0 + ks * 32);
            Af1[ks] = cvt8(w1 + ks * 32);
        }
    }
    float4 bias0 = *(const float4*)(proj_b + n0 + kq * 4);
    float4 bias1 = *(const float4*)(proj_b + n0 + 16 + kq * 4);

    __shared__ __attribute__((aligned(16))) unsigned short alds[32 * 512];
    __shared__ float esum[1344];
    for (int i = tid; i < 1344; i += 256) esum[i] = 0.f;
    __syncthreads();

    for (int mt = 0; mt < 42; mt++) {
        int mA = mt * 32;
        __syncthreads();
#pragma unroll
        for (int i = 0; i < 8; i++) {
            int idx = i * 256 + tid;
            int r = idx >> 6, c = idx & 63;
            *(uint4*)(alds + r * 512 + ((c ^ (r & 7)) * 8)) =
                *(const uint4*)(hseqb + (size_t)(mA + r) * 512 + c * 8);
        }
        __syncthreads();
        int rr = mhalf * 16 + col;
        int sw = rr & 7;
        f32x4 acc0 = {0.f, 0.f, 0.f, 0.f};
        f32x4 acc1 = {0.f, 0.f, 0.f, 0.f};
#pragma unroll
        for (int ks = 0; ks < 16; ks++) {
            int c = kq + 4 * ks;
            bf16x8 bf = *reinterpret_cast<const bf16x8*>(
                alds + rr * 512 + ((c ^ sw) * 8));
            acc0 = __builtin_amdgcn_mfma_f32_16x16x32_bf16(Af0[ks], bf, acc0, 0, 0, 0);
            acc1 = __builtin_amdgcn_mfma_f32_16x16x32_bf16(Af1[ks], bf, acc1, 0, 0, 0);
        }
        float e = __expf(acc0[0] + bias0.x) + __expf(acc0[1] + bias0.y) +
                  __expf(acc0[2] + bias0.z) + __expf(acc0[3] + bias0.w) +
                  __expf(acc1[0] + bias1.x) + __expf(acc1[1] + bias1.y) +
                  __expf(acc1[2] + bias1.z) + __expf(acc1[3] + bias1.w);
        atomicAdd(&esum[mA + rr], e);
    }
    __syncthreads();
    for (int i = tid; i < 1344; i += 256)
        partial[(size_t)blockIdx.x * 1344 + i] = esum[i];
}

// ---------------------------------------------------------------------------
__global__ __launch_bounds__(256) void sumexp_reduce_kernel(
        const float* __restrict__ partial, float* __restrict__ sumexp) {
    int m = blockIdx.x * 32 + (threadIdx.x >> 3);
    int sub = threadIdx.x & 7;
    float s = 0.f;
    for (int nb = sub; nb < 500; nb += 8) s += partial[(size_t)nb * 1344 + m];
    s += __shfl_xor(s, 1, 64);
    s += __shfl_xor(s, 2, 64);
    s += __shfl_xor(s, 4, 64);
    if (sub == 0) sumexp[m] = s;
}

// ---------------------------------------------------------------------------
__global__ __launch_bounds__(64) void loss_kernel(
        const unsigned short* __restrict__ hseqb,
        const float* __restrict__ proj_w, const float* __restrict__ proj_b,
        const float* __restrict__ sumexp, const int* __restrict__ seq_label,
        float* __restrict__ out) {
    int b = blockIdx.x;
    int lane = threadIdx.x;
    float num = 0.f, den = 0.f;
    for (int t = 0; t < T; t++) {
        int label = seq_label[b * T + t];
        const unsigned short* hp = hseqb + ((size_t)b * T + t) * 512;
        const float* wp = proj_w + (size_t)label * 512;
        float acc = 0.f;
#pragma unroll
        for (int i = 0; i < 8; i++)
            acc += bf16_to_f32(hp[lane + 64 * i]) * wp[lane + 64 * i];
        for (int off = 32; off > 0; off >>= 1) acc += __shfl_xor(acc, off, 64);
        if (lane == 0) {
            float nll = logf(sumexp[b * T + t]) - (acc + proj_b[label]);
            float mask = (label > 0) ? 1.f : 0.f;
            num += mask * nll;
            den += mask;
        }
    }
    if (lane == 0) atomicAdd(out, (num / (den + 1e-6f)) * (1.f / 64.f));
}

// ---------------------------------------------------------------------------
extern "C" void kernel_launch(void* const* d_in, const int* in_sizes, int n_in,
                              void* d_out, int out_size, void* d_ws, size_t ws_size,
                              hipStream_t stream) {
    const float* enc_h     = (const float*)d_in[0];
    const float* enc_out   = (const float*)d_in[1];
    const int*   seq_label = (const int*)d_in[3];
    const int*   dec_in    = (const int*)d_in[4];
    const float* style     = (const float*)d_in[5];
    const float* W_e2d_w   = (const float*)d_in[6];
    const float* W_e2d_b   = (const float*)d_in[7];
    const float* attn_W    = (const float*)d_in[8];
    const float* emb_table = (const float*)d_in[9];
    const float* w_ih      = (const float*)d_in[10];
    const float* w_hh      = (const float*)d_in[11];
    const float* b_ih      = (const float*)d_in[12];
    const float* b_hh      = (const float*)d_in[13];
    const float* proj_w    = (const float*)d_in[14];
    const float* proj_b    = (const float*)d_in[15];
    float* out = (float*)d_out;

    char* p = (char*)d_ws;
    float* partial = (float*)p;                    p += 500 * 1344 * 4;
    float* sumexp  = (float*)p;                    p += 1344 * 4 + 64;
    float* geT     = (float*)p;                    p += (size_t)21 * 2048 * 64 * 4;
    unsigned short* M_bf  = (unsigned short*)p;    p += (size_t)4096 * 512 * 2;
    unsigned short* wc2   = (unsigned short*)p;    p += (size_t)2048 * 1024 * 2;
    unsigned short* hseqb = (unsigned short*)p;    p += (size_t)1344 * 512 * 2;
    unsigned short* hb0   = (unsigned short*)p;    p += 64 * 512 * 2;
    unsigned short* hb1   = (unsigned short*)p;    p += 64 * 512 * 2;
    unsigned short* ctxb  = (unsigned short*)p;    p += 64 * 512 * 2;
    unsigned* bar = (unsigned*)p;                  p += 64 * 32 * 4;   // 64 flag lines

    hipMemsetAsync(out, 0, sizeof(float), stream);
    hipMemsetAsync(bar, 0, 64 * 32 * 4, stream);

    setup_kernel<<<3296, 256, 0, stream>>>(enc_h, style, W_e2d_w, W_e2d_b,
                                           enc_out, attn_W, w_ih, w_hh,
                                           emb_table, dec_in, b_ih, b_hh,
                                           hb0, wc2, M_bf, geT);

    // Regular launch (R7-proven): 64 blocks, 1/CU by LDS, co-resident on
    // 256 CUs; kernel uses only hand-rolled flag barriers.
    scan_kernel<<<64, 256, 0, stream>>>(M_bf, enc_out, wc2, geT,
                                        hb0, hb1, ctxb, hseqb, bar);

    proj_mfma_kernel<<<500, 256, 0, stream>>>(hseqb, proj_w, proj_b, partial);
    sumexp_reduce_kernel<<<42, 256, 0, stream>>>(partial, sumexp);
    loss_kernel<<<64, 64, 0, stream>>>(hseqb, proj_w, proj_b, sumexp, seq_label, out);
}

// Round 10
// 657.631 us; speedup vs baseline: 1.4566x; 1.0058x over previous
//
#include <hip/hip_runtime.h>
#include <hip/hip_bf16.h>
#include <math.h>

#define B 64
#define S 64
#define T 21
#define HID 512
#define VOCAB 32000

typedef __bf16 bf16x8 __attribute__((ext_vector_type(8)));
typedef float f32x4 __attribute__((ext_vector_type(4)));

union BF8 { unsigned short u[8]; bf16x8 v; uint4 q; };

__device__ __forceinline__ unsigned short f32_to_bf16_rne(float x) {
    union { float f; unsigned int u; } v;
    v.f = x;
    unsigned int u = v.u;
    unsigned int r = (u + 0x7FFFu + ((u >> 16) & 1u)) >> 16;
    return (unsigned short)r;
}

__device__ __forceinline__ float bf16_to_f32(unsigned short x) {
    union { unsigned int u; float f; } v;
    v.u = ((unsigned int)x) << 16;
    return v.f;
}

__device__ __forceinline__ bf16x8 cvt8(const float* p) {
    float4 f0 = *(const float4*)p;
    float4 f1 = *(const float4*)(p + 4);
    BF8 r;
    r.u[0] = f32_to_bf16_rne(f0.x); r.u[1] = f32_to_bf16_rne(f0.y);
    r.u[2] = f32_to_bf16_rne(f0.z); r.u[3] = f32_to_bf16_rne(f0.w);
    r.u[4] = f32_to_bf16_rne(f1.x); r.u[5] = f32_to_bf16_rne(f1.y);
    r.u[6] = f32_to_bf16_rne(f1.z); r.u[7] = f32_to_bf16_rne(f1.w);
    return r.v;
}

// --- Coherent (L1/L2-bypass, IF-coherent) access helpers (R8-proven) -------
__device__ __forceinline__ void ldg_coh_x4(uint4* r, const void* p) {
    asm volatile("global_load_dwordx4 %0, %1, off sc0 sc1"
                 : "=v"(*r) : "v"(p) : "memory");
}
__device__ __forceinline__ void ldg_coh_u32(unsigned* r, const void* p) {
    asm volatile("global_load_dword %0, %1, off sc0 sc1"
                 : "=v"(*r) : "v"(p) : "memory");
}
__device__ __forceinline__ void stg_coh_u32(void* p, unsigned v) {
    asm volatile("global_store_dword %0, %1, off sc0 sc1"
                 :: "v"(p), "v"(v) : "memory");
}
__device__ __forceinline__ void stg_coh_u16(void* p, unsigned v) {
    asm volatile("global_store_short %0, %1, off sc0 sc1"
                 :: "v"(p), "v"(v) : "memory");
}
__device__ __forceinline__ void wait_vm0() {
    asm volatile("s_waitcnt vmcnt(0)" ::: "memory");
    __builtin_amdgcn_sched_barrier(0);
}

// ---------------------------------------------------------------------------
// Fused setup (unchanged).
// ---------------------------------------------------------------------------
__global__ __launch_bounds__(256) void setup_kernel(
        const float* __restrict__ enc_h, const float* __restrict__ style,
        const float* __restrict__ W_e2d, const float* __restrict__ W_e2d_b,
        const float* __restrict__ enc_out, const float* __restrict__ attn_W,
        const float* __restrict__ w_ih, const float* __restrict__ w_hh,
        const float* __restrict__ emb_table, const int* __restrict__ dec_in,
        const float* __restrict__ b_ih, const float* __restrict__ b_hh,
        unsigned short* __restrict__ hb0, unsigned short* __restrict__ wc2,
        unsigned short* __restrict__ M_bf, float* __restrict__ geT) {
    int bid = blockIdx.x;
    int tid = threadIdx.x;
    __shared__ __attribute__((aligned(16))) float smem[640];

    if (bid < 64) {
        int b = bid;
        for (int i = tid; i < 512; i += 256) smem[i] = enc_h[b * 512 + i];
        if (tid < 128) smem[512 + tid] = style[b * 512 + 384 + tid];
        __syncthreads();
        for (int j = tid; j < 512; j += 256) {
            const float4* w4 = (const float4*)(W_e2d + (size_t)j * 640);
            float acc = 0.f;
#pragma unroll 4
            for (int k4 = 0; k4 < 160; k4++) {
                float4 w = w4[k4];
                float4 iv = *(const float4*)(smem + k4 * 4);
                acc += w.x * iv.x + w.y * iv.y + w.z * iv.z + w.w * iv.w;
            }
            hb0[b * 512 + j] = f32_to_bf16_rne(acc + W_e2d_b[j]);
        }
    } else if (bid < 2112) {
        int n = bid - 64;
        for (int k = tid; k < 1024; k += 256) {
            float v = (k < 512) ? w_ih[(size_t)n * 1024 + k]
                                : w_hh[(size_t)n * 512 + (k - 512)];
            wc2[(size_t)n * 1024 + k] = f32_to_bf16_rne(v);
        }
    } else if (bid < 2624) {
        int idx = bid - 2112;
        int xm = idx & 63, y = idx >> 6;
        int w = tid >> 6, lane = tid & 63;
        int col = lane & 15, kq = lane >> 4;
        int m0 = xm * 64 + w * 16;

        bf16x8 af[16];
        const float* arow = enc_out + (size_t)(m0 + col) * 512 + kq * 8;
#pragma unroll
        for (int ks = 0; ks < 16; ks++) af[ks] = cvt8(arow + ks * 32);

#pragma unroll
        for (int nt = 0; nt < 4; nt++) {
            int j0 = y * 64 + nt * 16;
            const float* brow = attn_W + (size_t)(j0 + col) * 512 + kq * 8;
            f32x4 acc = {0.f, 0.f, 0.f, 0.f};
#pragma unroll
            for (int ks = 0; ks < 16; ks++) {
                bf16x8 bf = cvt8(brow + ks * 32);
                acc = __builtin_amdgcn_mfma_f32_16x16x32_bf16(af[ks], bf, acc, 0, 0, 0);
            }
#pragma unroll
            for (int reg = 0; reg < 4; reg++) {
                int m = m0 + kq * 4 + reg;
                M_bf[(size_t)m * 512 + j0 + col] = f32_to_bf16_rne(acc[reg]);
            }
        }
    } else {
        int idx = bid - 2624;
        int mi = idx / 32, ni = idx - mi * 32;   // 21 m-tiles x 32 n-tiles
        int w = tid >> 6, lane = tid & 63;
        int col = lane & 15, kq = lane >> 4;
        int m0 = mi * 64 + w * 16;

        bf16x8 af[16];
        {
            int bt = m0 + col;
            int tok = dec_in[bt];
            const float* arow = emb_table + (size_t)tok * 512 + kq * 8;
#pragma unroll
            for (int ks = 0; ks < 16; ks++) af[ks] = cvt8(arow + ks * 32);
        }
#pragma unroll
        for (int nt = 0; nt < 4; nt++) {
            int n0 = ni * 64 + nt * 16;
            const float* brow = w_ih + (size_t)(n0 + col) * 1024 + 512 + kq * 8;
            f32x4 acc = {0.f, 0.f, 0.f, 0.f};
#pragma unroll
            for (int ks = 0; ks < 16; ks++) {
                bf16x8 bf = cvt8(brow + ks * 32);
                acc = __builtin_amdgcn_mfma_f32_16x16x32_bf16(af[ks], bf, acc, 0, 0, 0);
            }
#pragma unroll
            for (int reg = 0; reg < 4; reg++) {
                int m = m0 + kq * 4 + reg;      // bt index
                int n = n0 + col;
                int bb = m / T, tt = m - bb * T;
                geT[((size_t)tt * 2048 + n) * 64 + bb] = acc[reg] + b_ih[n] + b_hh[n];
            }
        }
    }
}

// ---------------------------------------------------------------------------
// Persistent scan (R8-proven fence-free protocol). One change vs R8: the
// __syncthreads after the hls write is removed — hls slice [w*128,w*128+128)
// is written and read ONLY by wave w (lgkmcnt orders ds_write->ds_read
// within the wave's lockstep instruction stream), so no cross-wave hazard.
// ---------------------------------------------------------------------------
__global__ __launch_bounds__(256, 1) void scan_kernel(
        const unsigned short* __restrict__ M_bf,
        const float* __restrict__ enc_out,
        const unsigned short* __restrict__ wc2,
        const float* __restrict__ geT,
        unsigned short* __restrict__ hb0, unsigned short* __restrict__ hb1,
        unsigned short* __restrict__ ctxb, unsigned short* __restrict__ hseqb,
        unsigned* __restrict__ flags) {
    const int bk = blockIdx.x;
    const int tid = threadIdx.x;
    const int b = bk, u0 = bk * 8;
    const int lane = tid & 63, w = tid >> 6;
    const int col = lane & 15, kq = lane >> 4;

    __shared__ __attribute__((aligned(16))) unsigned short Mlds[64 * 512];
    __shared__ __attribute__((aligned(16))) unsigned short Wlds[32 * 1024];
    __shared__ __attribute__((aligned(16))) float fscr[2112];
    __shared__ float scp[4][64];
    __shared__ float hls[512];

    // Stage M[b] (swizzled: chunk' = c ^ (row&7))
#pragma unroll
    for (int i = 0; i < 16; i++) {
        int idx = i * 256 + tid;
        int r = idx >> 6, c = idx & 63;
        *(uint4*)(Mlds + r * 512 + ((c ^ (r & 7)) * 8)) =
            *(const uint4*)(M_bf + ((size_t)(b * 64 + r)) * 512 + c * 8);
    }
    // Stage W rows (swizzled)
#pragma unroll
    for (int i = 0; i < 16; i++) {
        int idx = i * 256 + tid;
        int r = idx >> 7, c = idx & 127;
        int gr = (r >> 3) * 512 + u0 + (r & 7);
        *(uint4*)(Wlds + r * 1024 + ((c ^ (r & 7)) * 8)) =
            *(const uint4*)(wc2 + (size_t)gr * 1024 + c * 8);
    }

    // In-register LSTM lane mapping: lane (col,kq) handles unit u0+(col&7),
    // batches b0+{0,1} (col<8) or b0+{2,3} (col>=8).
    float creg0 = 0.f, creg1 = 0.f;
    const int uloc = col & 7;
    const bool r01 = (col < 8);
    const int b0 = w * 16 + kq * 4;
    __syncthreads();

    unsigned bcnt = 0;
    for (int t = 0; t < T; t++) {
        unsigned short* hcur = (t & 1) ? hb1 : hb0;
        unsigned short* hnxt = (t & 1) ? hb0 : hb1;

        // ---- step-start loads: hb is remote-written -> coherent loads ----
        unsigned hw;
        ldg_coh_u32(&hw, (const unsigned*)hcur + b * 256 + tid);
        uint4 hfr[16];
        {
            const unsigned short* arow_h = hcur + (size_t)(w * 16 + col) * 512 + kq * 8;
#pragma unroll
            for (int j = 0; j < 16; j++) ldg_coh_x4(&hfr[j], arow_h + j * 32);
        }
        const float* ge = geT + (size_t)t * 2048 * 64;   // L2-warm (no invs)
        const int gA = r01 ? 0 : 1, gB = r01 ? 2 : 3;
        float4 geA4 = *(const float4*)(ge + (size_t)(gA * 512 + u0 + uloc) * 64 + b0);
        float4 geB4 = *(const float4*)(ge + (size_t)(gB * 512 + u0 + uloc) * 64 + b0);
        wait_vm0();
        hls[2 * tid]     = bf16_to_f32((unsigned short)(hw & 0xffffu));
        hls[2 * tid + 1] = bf16_to_f32((unsigned short)(hw >> 16));
        // no __syncthreads: hls slice is wave-local (write+read by wave w only)

        // ---------------- phase 1: attention for batch b ----------------
        {   // scores: s = lane, q = w covers d-range q*128..+128
            float acc = 0.f;
#pragma unroll
            for (int i = 0; i < 16; i++) {
                int c = w * 16 + i;
                BF8 mp;
                mp.q = *(const uint4*)(Mlds + lane * 512 + ((c ^ (lane & 7)) * 8));
                const float* hq = hls + w * 128 + i * 8;
#pragma unroll
                for (int j = 0; j < 8; j++) acc += bf16_to_f32(mp.u[j]) * hq[j];
            }
            scp[w][lane] = acc;
        }
        __syncthreads();
        // redundant per-wave softmax (identical ops/results in every wave)
        float a_l;
        {
            float v = scp[0][lane] + scp[1][lane] + scp[2][lane] + scp[3][lane];
            float m = v;
            for (int off = 32; off > 0; off >>= 1) m = fmaxf(m, __shfl_xor(m, off, 64));
            float e = __expf(v - m);
            float ss = e;
            for (int off = 32; off > 0; off >>= 1) ss += __shfl_xor(ss, off, 64);
            a_l = e / ss;
        }
        {   // ctx partials: w covers s-range, lane covers d = lane*8..+8
            float cp[8] = {0, 0, 0, 0, 0, 0, 0, 0};
#pragma unroll 4
            for (int si = 0; si < 16; si++) {
                int s = w * 16 + si;
                float a = __shfl(a_l, s, 64);
                const float* ep = enc_out + ((size_t)(b * 64 + s)) * 512 + lane * 8;
                float4 e0 = *(const float4*)ep;
                float4 e1 = *(const float4*)(ep + 4);
                cp[0] += a * e0.x; cp[1] += a * e0.y; cp[2] += a * e0.z; cp[3] += a * e0.w;
                cp[4] += a * e1.x; cp[5] += a * e1.y; cp[6] += a * e1.z; cp[7] += a * e1.w;
            }
            // lane-major, stride 66: conflict-free writes and reads
#pragma unroll
            for (int j = 0; j < 8; j++) fscr[w * 528 + j * 66 + lane] = cp[j];
        }
        __syncthreads();
        {   // reduce 4 partials, write ctx (coherent write-through store)
            int l0 = tid >> 2, j0 = (2 * tid) & 7;
            float v0 = fscr[j0 * 66 + l0] + fscr[528 + j0 * 66 + l0] +
                       fscr[1056 + j0 * 66 + l0] + fscr[1584 + j0 * 66 + l0];
            float v1 = fscr[(j0 + 1) * 66 + l0] + fscr[528 + (j0 + 1) * 66 + l0] +
                       fscr[1056 + (j0 + 1) * 66 + l0] + fscr[1584 + (j0 + 1) * 66 + l0];
            unsigned pack = (unsigned)f32_to_bf16_rne(v0) |
                            ((unsigned)f32_to_bf16_rne(v1) << 16);
            stg_coh_u32(ctxb + b * 512 + tid * 2, pack);
        }

        // ---- barrier 1: drain stores, arrive, per-wave partial wait ----
        bcnt++;
        wait_vm0();          // ctx stores acked at coherence point
        __syncthreads();     // all 256 threads' stores drained
        if (tid == 0)
            __hip_atomic_store(&flags[bk * 32], bcnt, __ATOMIC_RELAXED,
                               __HIP_MEMORY_SCOPE_AGENT);
        if (kq == 0) {   // lanes 0..15 of each wave poll its 16 producers
            const unsigned* f = &flags[(w * 16 + col) * 32];
            while (__hip_atomic_load(f, __ATOMIC_RELAXED, __HIP_MEMORY_SCOPE_AGENT) < bcnt)
                __builtin_amdgcn_s_sleep(2);
        }
        // no acquire fence: ctx read below bypasses L1/L2

        // ---------------- phase 3: gates MFMA + in-register LSTM ----------------
        f32x4 acc0 = {0.f, 0.f, 0.f, 0.f};
        f32x4 acc1 = {0.f, 0.f, 0.f, 0.f};
        {
            uint4 cfr[16];
            const unsigned short* arow_c = ctxb + (size_t)(w * 16 + col) * 512 + kq * 8;
#pragma unroll
            for (int j = 0; j < 16; j++) ldg_coh_x4(&cfr[j], arow_c + j * 32);

            int sw0 = col & 7;
            // h-part first (register operands): overlaps the cfr load latency
#pragma unroll
            for (int ks = 16; ks < 32; ks++) {
                BF8 a8; a8.q = hfr[ks - 16];
                int c = kq + 4 * ks;
                bf16x8 bf0 = *reinterpret_cast<const bf16x8*>(
                    Wlds + col * 1024 + ((c ^ sw0) * 8));
                bf16x8 bf1 = *reinterpret_cast<const bf16x8*>(
                    Wlds + (16 + col) * 1024 + ((c ^ sw0) * 8));
                acc0 = __builtin_amdgcn_mfma_f32_16x16x32_bf16(a8.v, bf0, acc0, 0, 0, 0);
                acc1 = __builtin_amdgcn_mfma_f32_16x16x32_bf16(a8.v, bf1, acc1, 0, 0, 0);
            }
            wait_vm0();      // cfr loads landed
#pragma unroll
            for (int ks = 0; ks < 16; ks++) {
                BF8 a8; a8.q = cfr[ks];
                int c = kq + 4 * ks;
                bf16x8 bf0 = *reinterpret_cast<const bf16x8*>(
                    Wlds + col * 1024 + ((c ^ sw0) * 8));
                bf16x8 bf1 = *reinterpret_cast<const bf16x8*>(
                    Wlds + (16 + col) * 1024 + ((c ^ sw0) * 8));
                acc0 = __builtin_amdgcn_mfma_f32_16x16x32_bf16(a8.v, bf0, acc0, 0, 0, 0);
                acc1 = __builtin_amdgcn_mfma_f32_16x16x32_bf16(a8.v, bf1, acc1, 0, 0, 0);
            }
        }
        {   // gates + in-register LSTM (shfl_xor(8) exchange)
            float go0[4], go1[4];
            float geAv[4] = {geA4.x, geA4.y, geA4.z, geA4.w};
            float geBv[4] = {geB4.x, geB4.y, geB4.z, geB4.w};
#pragma unroll
            for (int rg = 0; rg < 4; rg++) {
                go0[rg] = acc0[rg] + geAv[rg];
                go1[rg] = acc1[rg] + geBv[rg];
            }
            float sh0 = __shfl_xor(r01 ? go0[2] : go0[0], 8, 64);
            float sh1 = __shfl_xor(r01 ? go0[3] : go0[1], 8, 64);
            float sh2 = __shfl_xor(r01 ? go1[2] : go1[0], 8, 64);
            float sh3 = __shfl_xor(r01 ? go1[3] : go1[1], 8, 64);
            int u = u0 + uloc;
            int bA = b0 + (r01 ? 0 : 2);
            {
                float G0 = r01 ? go0[0] : sh0;
                float G1 = r01 ? sh0 : go0[2];
                float G2 = r01 ? go1[0] : sh2;
                float G3 = r01 ? sh2 : go1[2];
                float ig = 1.f / (1.f + __expf(-G0));
                float fg = 1.f / (1.f + __expf(-G1));
                float gt = tanhf(G2);
                float og = 1.f / (1.f + __expf(-G3));
                creg0 = fg * creg0 + ig * gt;
                float hn = og * tanhf(creg0);
                unsigned short hv = f32_to_bf16_rne(hn);
                stg_coh_u16(hnxt + bA * 512 + u, (unsigned)hv);
                hseqb[((size_t)bA * T + t) * 512 + u] = hv;
            }
            {
                float G0 = r01 ? go0[1] : sh1;
                float G1 = r01 ? sh1 : go0[3];
                float G2 = r01 ? go1[1] : sh3;
                float G3 = r01 ? sh3 : go1[3];
                float ig = 1.f / (1.f + __expf(-G0));
                float fg = 1.f / (1.f + __expf(-G1));
                float gt = tanhf(G2);
                float og = 1.f / (1.f + __expf(-G3));
                creg1 = fg * creg1 + ig * gt;
                float hn = og * tanhf(creg1);
                unsigned short hv = f32_to_bf16_rne(hn);
                int bB = bA + 1;
                stg_coh_u16(hnxt + bB * 512 + u, (unsigned)hv);
                hseqb[((size_t)bB * T + t) * 512 + u] = hv;
            }
        }

        // ---- barrier 2: full (h is all-to-all); skip after last step ----
        bcnt++;
        if (t < T - 1) {
            wait_vm0();      // h stores acked at coherence point
            __syncthreads();
            if (tid == 0)
                __hip_atomic_store(&flags[bk * 32], bcnt, __ATOMIC_RELAXED,
                                   __HIP_MEMORY_SCOPE_AGENT);
            if (tid < 64) {
                const unsigned* f = &flags[tid * 32];
                while (__hip_atomic_load(f, __ATOMIC_RELAXED, __HIP_MEMORY_SCOPE_AGENT) < bcnt)
                    __builtin_amdgcn_s_sleep(2);
            }
            __syncthreads();
        }
    }
}

// ---------------------------------------------------------------------------
// Projection + exp-sum. Staging via global_load_lds width=16 with
// PRE-SWIZZLED SOURCE + linear LDS dest (rule-#21-correct pairing): lane l
// of the wave handling row r loads global chunk l^(r&7) into LDS chunk l,
// so LDS chunk j holds global chunk j^(r&7) — identical layout to the
// staged-copy version; reads unchanged. Async, no VGPR round-trip.
// ---------------------------------------------------------------------------
__global__ __launch_bounds__(256) void proj_mfma_kernel(
        const unsigned short* __restrict__ hseqb,
        const float* __restrict__ proj_w,
        const float* __restrict__ proj_b,
        float* __restrict__ partial) {
    int tid = threadIdx.x;
    int wv = tid >> 6, lane = tid & 63;
    int col = lane & 15, kq = lane >> 4;
    int nhalf = wv & 1, mhalf = wv >> 1;
    int n0 = blockIdx.x * 64 + nhalf * 32;

    bf16x8 Af0[16], Af1[16];
    {
        const float* w0 = proj_w + (size_t)(n0 + col) * 512 + kq * 8;
        const float* w1 = proj_w + (size_t)(n0 + 16 + col) * 512 + kq * 8;
#pragma unroll
        for (int ks = 0; ks < 16; ks++) {
            Af0[ks] = cvt8(w0 + ks * 32);
            Af1[ks] = cvt8(w1 + ks * 32);
        }
    }
    float4 bias0 = *(const float4*)(proj_b + n0 + kq * 4);
    float4 bias1 = *(const float4*)(proj_b + n0 + 16 + kq * 4);

    __shared__ __attribute__((aligned(16))) unsigned short alds[32 * 512];
    __shared__ float esum[1344];
    for (int i = tid; i < 1344; i += 256) esum[i] = 0.f;
    __syncthreads();

    for (int mt = 0; mt < 42; mt++) {
        int mA = mt * 32;
        __syncthreads();
#pragma unroll
        for (int i = 0; i < 8; i++) {
            int r = i * 4 + wv;                 // wave-uniform row
            int cs = lane ^ (r & 7);            // pre-swizzled source chunk
            __builtin_amdgcn_global_load_lds(
                (const __attribute__((address_space(1))) void*)
                    (hseqb + (size_t)(mA + r) * 512 + cs * 8),
                (__attribute__((address_space(3))) void*)(alds + r * 512),
                16, 0, 0);
        }
        asm volatile("s_waitcnt vmcnt(0)" ::: "memory");
        __syncthreads();
        int rr = mhalf * 16 + col;
        int sw = rr & 7;
        f32x4 acc0 = {0.f, 0.f, 0.f, 0.f};
        f32x4 acc1 = {0.f, 0.f, 0.f, 0.f};
#pragma unroll
        for (int ks = 0; ks < 16; ks++) {
            int c = kq + 4 * ks;
            bf16x8 bf = *reinterpret_cast<const bf16x8*>(
                alds + rr * 512 + ((c ^ sw) * 8));
            acc0 = __builtin_amdgcn_mfma_f32_16x16x32_bf16(Af0[ks], bf, acc0, 0, 0, 0);
            acc1 = __builtin_amdgcn_mfma_f32_16x16x32_bf16(Af1[ks], bf, acc1, 0, 0, 0);
        }
        float e = __expf(acc0[0] + bias0.x) + __expf(acc0[1] + bias0.y) +
                  __expf(acc0[2] + bias0.z) + __expf(acc0[3] + bias0.w) +
                  __expf(acc1[0] + bias1.x) + __expf(acc1[1] + bias1.y) +
                  __expf(acc1[2] + bias1.z) + __expf(acc1[3] + bias1.w);
        atomicAdd(&esum[mA + rr], e);
    }
    __syncthreads();
    for (int i = tid; i < 1344; i += 256)
        partial[(size_t)blockIdx.x * 1344 + i] = esum[i];
}

// ---------------------------------------------------------------------------
// Coalesced reduce: thread = m (consecutive threads -> consecutive floats),
// loop over the 500 partial blocks. grid(6) x block(256) covers 1344 m.
// ---------------------------------------------------------------------------
__global__ __launch_bounds__(256) void sumexp_reduce_kernel(
        const float* __restrict__ partial, float* __restrict__ sumexp) {
    int m = blockIdx.x * 256 + threadIdx.x;
    if (m >= 1344) return;
    float s = 0.f;
#pragma unroll 4
    for (int nb = 0; nb < 500; nb++) s += partial[(size_t)nb * 1344 + m];
    sumexp[m] = s;
}

// ---------------------------------------------------------------------------
// Loss, parallelized: one block per (b,t) computes the label dot + masked
// nll; a single tiny block finalizes the per-batch means.
// ---------------------------------------------------------------------------
__global__ __launch_bounds__(64) void loss_dot_kernel(
        const unsigned short* __restrict__ hseqb,
        const float* __restrict__ proj_w, const float* __restrict__ proj_b,
        const float* __restrict__ sumexp, const int* __restrict__ seq_label,
        float2* __restrict__ nll2) {
    int bid = blockIdx.x;            // = b*T + t
    int lane = threadIdx.x;
    int label = seq_label[bid];
    const unsigned short* hp = hseqb + (size_t)bid * 512;
    const float* wp = proj_w + (size_t)label * 512;
    float acc = 0.f;
#pragma unroll
    for (int i = 0; i < 8; i++)
        acc += bf16_to_f32(hp[lane + 64 * i]) * wp[lane + 64 * i];
    for (int off = 32; off > 0; off >>= 1) acc += __shfl_xor(acc, off, 64);
    if (lane == 0) {
        float mask = (label > 0) ? 1.f : 0.f;
        float nll = logf(sumexp[bid]) - (acc + proj_b[label]);
        nll2[bid] = make_float2(mask * nll, mask);
    }
}

__global__ __launch_bounds__(64) void loss_final_kernel(
        const float2* __restrict__ nll2, float* __restrict__ out) {
    int b = threadIdx.x;             // 0..63
    float num = 0.f, den = 0.f;
    for (int t = 0; t < T; t++) {
        float2 v = nll2[b * T + t];
        num += v.x; den += v.y;
    }
    float l = (num / (den + 1e-6f)) * (1.f / 64.f);
    for (int off = 32; off > 0; off >>= 1) l += __shfl_xor(l, off, 64);
    if (b == 0) *out = l;
}

// ---------------------------------------------------------------------------
extern "C" void kernel_launch(void* const* d_in, const int* in_sizes, int n_in,
                              void* d_out, int out_size, void* d_ws, size_t ws_size,
                              hipStream_t stream) {
    const float* enc_h     = (const float*)d_in[0];
    const float* enc_out   = (const float*)d_in[1];
    const int*   seq_label = (const int*)d_in[3];
    const int*   dec_in    = (const int*)d_in[4];
    const float* style     = (const float*)d_in[5];
    const float* W_e2d_w   = (const float*)d_in[6];
    const float* W_e2d_b   = (const float*)d_in[7];
    const float* attn_W    = (const float*)d_in[8];
    const float* emb_table = (const float*)d_in[9];
    const float* w_ih      = (const float*)d_in[10];
    const float* w_hh      = (const float*)d_in[11];
    const float* b_ih      = (const float*)d_in[12];
    const float* b_hh      = (const float*)d_in[13];
    const float* proj_w    = (const float*)d_in[14];
    const float* proj_b    = (const float*)d_in[15];
    float* out = (float*)d_out;

    char* p = (char*)d_ws;
    float* partial = (float*)p;                    p += 500 * 1344 * 4;
    float* sumexp  = (float*)p;                    p += 1344 * 4 + 64;
    float* geT     = (float*)p;                    p += (size_t)21 * 2048 * 64 * 4;
    unsigned short* M_bf  = (unsigned short*)p;    p += (size_t)4096 * 512 * 2;
    unsigned short* wc2   = (unsigned short*)p;    p += (size_t)2048 * 1024 * 2;
    unsigned short* hseqb = (unsigned short*)p;    p += (size_t)1344 * 512 * 2;
    unsigned short* hb0   = (unsigned short*)p;    p += 64 * 512 * 2;
    unsigned short* hb1   = (unsigned short*)p;    p += 64 * 512 * 2;
    unsigned short* ctxb  = (unsigned short*)p;    p += 64 * 512 * 2;
    unsigned* bar = (unsigned*)p;                  p += 64 * 32 * 4;   // 64 flag lines
    float2* nll2 = (float2*)p;                     p += 1344 * 8;

    hipMemsetAsync(out, 0, sizeof(float), stream);
    hipMemsetAsync(bar, 0, 64 * 32 * 4, stream);

    setup_kernel<<<3296, 256, 0, stream>>>(enc_h, style, W_e2d_w, W_e2d_b,
                                           enc_out, attn_W, w_ih, w_hh,
                                           emb_table, dec_in, b_ih, b_hh,
                                           hb0, wc2, M_bf, geT);

    // Regular launch (R7-proven): 64 blocks, 1/CU by LDS, co-resident on
    // 256 CUs; kernel uses only hand-rolled flag barriers.
    scan_kernel<<<64, 256, 0, stream>>>(M_bf, enc_out, wc2, geT,
                                        hb0, hb1, ctxb, hseqb, bar);

    proj_mfma_kernel<<<500, 256, 0, stream>>>(hseqb, proj_w, proj_b, partial);
    sumexp_reduce_kernel<<<6, 256, 0, stream>>>(partial, sumexp);
    loss_dot_kernel<<<1344, 64, 0, stream>>>(hseqb, proj_w, proj_b, sumexp,
                                             seq_label, nll2);
    loss_final_kernel<<<1, 64, 0, stream>>>(nll2, out);
}

// Round 11
// 626.298 us; speedup vs baseline: 1.5294x; 1.0500x over previous
//
#include <hip/hip_runtime.h>
#include <hip/hip_bf16.h>
#include <math.h>

#define B 64
#define S 64
#define T 21
#define HID 512
#define VOCAB 32000

typedef __bf16 bf16x8 __attribute__((ext_vector_type(8)));
typedef float f32x4 __attribute__((ext_vector_type(4)));

union BF8 { unsigned short u[8]; bf16x8 v; uint4 q; };

__device__ __forceinline__ unsigned short f32_to_bf16_rne(float x) {
    union { float f; unsigned int u; } v;
    v.f = x;
    unsigned int u = v.u;
    unsigned int r = (u + 0x7FFFu + ((u >> 16) & 1u)) >> 16;
    return (unsigned short)r;
}

__device__ __forceinline__ float bf16_to_f32(unsigned short x) {
    union { unsigned int u; float f; } v;
    v.u = ((unsigned int)x) << 16;
    return v.f;
}

__device__ __forceinline__ bf16x8 cvt8(const float* p) {
    float4 f0 = *(const float4*)p;
    float4 f1 = *(const float4*)(p + 4);
    BF8 r;
    r.u[0] = f32_to_bf16_rne(f0.x); r.u[1] = f32_to_bf16_rne(f0.y);
    r.u[2] = f32_to_bf16_rne(f0.z); r.u[3] = f32_to_bf16_rne(f0.w);
    r.u[4] = f32_to_bf16_rne(f1.x); r.u[5] = f32_to_bf16_rne(f1.y);
    r.u[6] = f32_to_bf16_rne(f1.z); r.u[7] = f32_to_bf16_rne(f1.w);
    return r.v;
}

// --- Coherent (L1/L2-bypass, IF-coherent) access helpers (R8-proven) -------
__device__ __forceinline__ void ldg_coh_x4(uint4* r, const void* p) {
    asm volatile("global_load_dwordx4 %0, %1, off sc0 sc1"
                 : "=v"(*r) : "v"(p) : "memory");
}
__device__ __forceinline__ void ldg_coh_x2(float2* r, const void* p) {
    asm volatile("global_load_dwordx2 %0, %1, off sc0 sc1"
                 : "=v"(*r) : "v"(p) : "memory");
}
__device__ __forceinline__ void ldg_coh_u32(unsigned* r, const void* p) {
    asm volatile("global_load_dword %0, %1, off sc0 sc1"
                 : "=v"(*r) : "v"(p) : "memory");
}
__device__ __forceinline__ void stg_coh_u32(void* p, unsigned v) {
    asm volatile("global_store_dword %0, %1, off sc0 sc1"
                 :: "v"(p), "v"(v) : "memory");
}
__device__ __forceinline__ void stg_coh_x2(void* p, float2 v) {
    asm volatile("global_store_dwordx2 %0, %1, off sc0 sc1"
                 :: "v"(p), "v"(v) : "memory");
}
__device__ __forceinline__ void stg_coh_u16(void* p, unsigned v) {
    asm volatile("global_store_short %0, %1, off sc0 sc1"
                 :: "v"(p), "v"(v) : "memory");
}
__device__ __forceinline__ void wait_vm0() {
    asm volatile("s_waitcnt vmcnt(0)" ::: "memory");
    __builtin_amdgcn_sched_barrier(0);
}

// ---------------------------------------------------------------------------
// Fused setup (compute unchanged). Block 0 additionally zeroes the barrier
// flag lines + done counter (replaces the hipMemsetAsync node): plain
// stores, flushed by the end-of-kernel writeback, read by scan's bypass
// polls from the coherence point.
// ---------------------------------------------------------------------------
__global__ __launch_bounds__(256) void setup_kernel(
        const float* __restrict__ enc_h, const float* __restrict__ style,
        const float* __restrict__ W_e2d, const float* __restrict__ W_e2d_b,
        const float* __restrict__ enc_out, const float* __restrict__ attn_W,
        const float* __restrict__ w_ih, const float* __restrict__ w_hh,
        const float* __restrict__ emb_table, const int* __restrict__ dec_in,
        const float* __restrict__ b_ih, const float* __restrict__ b_hh,
        unsigned short* __restrict__ hb0, unsigned short* __restrict__ wc2,
        unsigned short* __restrict__ M_bf, float* __restrict__ geT,
        unsigned* __restrict__ bar) {
    int bid = blockIdx.x;
    int tid = threadIdx.x;
    __shared__ __attribute__((aligned(16))) float smem[640];

    if (bid < 64) {
        int b = bid;
        if (b == 0) {   // zero 64 flag lines (2048 u32) + done counter (+64)
            for (int i = tid; i < 2048 + 64; i += 256) bar[i] = 0;
        }
        for (int i = tid; i < 512; i += 256) smem[i] = enc_h[b * 512 + i];
        if (tid < 128) smem[512 + tid] = style[b * 512 + 384 + tid];
        __syncthreads();
        for (int j = tid; j < 512; j += 256) {
            const float4* w4 = (const float4*)(W_e2d + (size_t)j * 640);
            float acc = 0.f;
#pragma unroll 4
            for (int k4 = 0; k4 < 160; k4++) {
                float4 w = w4[k4];
                float4 iv = *(const float4*)(smem + k4 * 4);
                acc += w.x * iv.x + w.y * iv.y + w.z * iv.z + w.w * iv.w;
            }
            hb0[b * 512 + j] = f32_to_bf16_rne(acc + W_e2d_b[j]);
        }
    } else if (bid < 2112) {
        int n = bid - 64;
        for (int k = tid; k < 1024; k += 256) {
            float v = (k < 512) ? w_ih[(size_t)n * 1024 + k]
                                : w_hh[(size_t)n * 512 + (k - 512)];
            wc2[(size_t)n * 1024 + k] = f32_to_bf16_rne(v);
        }
    } else if (bid < 2624) {
        int idx = bid - 2112;
        int xm = idx & 63, y = idx >> 6;
        int w = tid >> 6, lane = tid & 63;
        int col = lane & 15, kq = lane >> 4;
        int m0 = xm * 64 + w * 16;

        bf16x8 af[16];
        const float* arow = enc_out + (size_t)(m0 + col) * 512 + kq * 8;
#pragma unroll
        for (int ks = 0; ks < 16; ks++) af[ks] = cvt8(arow + ks * 32);

#pragma unroll
        for (int nt = 0; nt < 4; nt++) {
            int j0 = y * 64 + nt * 16;
            const float* brow = attn_W + (size_t)(j0 + col) * 512 + kq * 8;
            f32x4 acc = {0.f, 0.f, 0.f, 0.f};
#pragma unroll
            for (int ks = 0; ks < 16; ks++) {
                bf16x8 bf = cvt8(brow + ks * 32);
                acc = __builtin_amdgcn_mfma_f32_16x16x32_bf16(af[ks], bf, acc, 0, 0, 0);
            }
#pragma unroll
            for (int reg = 0; reg < 4; reg++) {
                int m = m0 + kq * 4 + reg;
                M_bf[(size_t)m * 512 + j0 + col] = f32_to_bf16_rne(acc[reg]);
            }
        }
    } else {
        int idx = bid - 2624;
        int mi = idx / 32, ni = idx - mi * 32;   // 21 m-tiles x 32 n-tiles
        int w = tid >> 6, lane = tid & 63;
        int col = lane & 15, kq = lane >> 4;
        int m0 = mi * 64 + w * 16;

        bf16x8 af[16];
        {
            int bt = m0 + col;
            int tok = dec_in[bt];
            const float* arow = emb_table + (size_t)tok * 512 + kq * 8;
#pragma unroll
            for (int ks = 0; ks < 16; ks++) af[ks] = cvt8(arow + ks * 32);
        }
#pragma unroll
        for (int nt = 0; nt < 4; nt++) {
            int n0 = ni * 64 + nt * 16;
            const float* brow = w_ih + (size_t)(n0 + col) * 1024 + 512 + kq * 8;
            f32x4 acc = {0.f, 0.f, 0.f, 0.f};
#pragma unroll
            for (int ks = 0; ks < 16; ks++) {
                bf16x8 bf = cvt8(brow + ks * 32);
                acc = __builtin_amdgcn_mfma_f32_16x16x32_bf16(af[ks], bf, acc, 0, 0, 0);
            }
#pragma unroll
            for (int reg = 0; reg < 4; reg++) {
                int m = m0 + kq * 4 + reg;      // bt index
                int n = n0 + col;
                int bb = m / T, tt = m - bb * T;
                geT[((size_t)tt * 2048 + n) * 64 + bb] = acc[reg] + b_ih[n] + b_hh[n];
            }
        }
    }
}

// ---------------------------------------------------------------------------
// Persistent scan (R10-proven: fence-free sc0sc1 protocol, regular launch,
// no hls barrier). Unchanged this round.
// ---------------------------------------------------------------------------
__global__ __launch_bounds__(256, 1) void scan_kernel(
        const unsigned short* __restrict__ M_bf,
        const float* __restrict__ enc_out,
        const unsigned short* __restrict__ wc2,
        const float* __restrict__ geT,
        unsigned short* __restrict__ hb0, unsigned short* __restrict__ hb1,
        unsigned short* __restrict__ ctxb, unsigned short* __restrict__ hseqb,
        unsigned* __restrict__ flags) {
    const int bk = blockIdx.x;
    const int tid = threadIdx.x;
    const int b = bk, u0 = bk * 8;
    const int lane = tid & 63, w = tid >> 6;
    const int col = lane & 15, kq = lane >> 4;

    __shared__ __attribute__((aligned(16))) unsigned short Mlds[64 * 512];
    __shared__ __attribute__((aligned(16))) unsigned short Wlds[32 * 1024];
    __shared__ __attribute__((aligned(16))) float fscr[2112];
    __shared__ float scp[4][64];
    __shared__ float hls[512];

    // Stage M[b] (swizzled: chunk' = c ^ (row&7))
#pragma unroll
    for (int i = 0; i < 16; i++) {
        int idx = i * 256 + tid;
        int r = idx >> 6, c = idx & 63;
        *(uint4*)(Mlds + r * 512 + ((c ^ (r & 7)) * 8)) =
            *(const uint4*)(M_bf + ((size_t)(b * 64 + r)) * 512 + c * 8);
    }
    // Stage W rows (swizzled)
#pragma unroll
    for (int i = 0; i < 16; i++) {
        int idx = i * 256 + tid;
        int r = idx >> 7, c = idx & 127;
        int gr = (r >> 3) * 512 + u0 + (r & 7);
        *(uint4*)(Wlds + r * 1024 + ((c ^ (r & 7)) * 8)) =
            *(const uint4*)(wc2 + (size_t)gr * 1024 + c * 8);
    }

    float creg0 = 0.f, creg1 = 0.f;
    const int uloc = col & 7;
    const bool r01 = (col < 8);
    const int b0 = w * 16 + kq * 4;
    __syncthreads();

    unsigned bcnt = 0;
    for (int t = 0; t < T; t++) {
        unsigned short* hcur = (t & 1) ? hb1 : hb0;
        unsigned short* hnxt = (t & 1) ? hb0 : hb1;

        // ---- step-start loads: hb is remote-written -> coherent loads ----
        unsigned hw;
        ldg_coh_u32(&hw, (const unsigned*)hcur + b * 256 + tid);
        uint4 hfr[16];
        {
            const unsigned short* arow_h = hcur + (size_t)(w * 16 + col) * 512 + kq * 8;
#pragma unroll
            for (int j = 0; j < 16; j++) ldg_coh_x4(&hfr[j], arow_h + j * 32);
        }
        const float* ge = geT + (size_t)t * 2048 * 64;   // L2-warm (no invs)
        const int gA = r01 ? 0 : 1, gB = r01 ? 2 : 3;
        float4 geA4 = *(const float4*)(ge + (size_t)(gA * 512 + u0 + uloc) * 64 + b0);
        float4 geB4 = *(const float4*)(ge + (size_t)(gB * 512 + u0 + uloc) * 64 + b0);
        wait_vm0();
        hls[2 * tid]     = bf16_to_f32((unsigned short)(hw & 0xffffu));
        hls[2 * tid + 1] = bf16_to_f32((unsigned short)(hw >> 16));
        // no __syncthreads: hls slice is wave-local (write+read by wave w only)

        // ---------------- phase 1: attention for batch b ----------------
        {   // scores: s = lane, q = w covers d-range q*128..+128
            float acc = 0.f;
#pragma unroll
            for (int i = 0; i < 16; i++) {
                int c = w * 16 + i;
                BF8 mp;
                mp.q = *(const uint4*)(Mlds + lane * 512 + ((c ^ (lane & 7)) * 8));
                const float* hq = hls + w * 128 + i * 8;
#pragma unroll
                for (int j = 0; j < 8; j++) acc += bf16_to_f32(mp.u[j]) * hq[j];
            }
            scp[w][lane] = acc;
        }
        __syncthreads();
        // redundant per-wave softmax (identical ops/results in every wave)
        float a_l;
        {
            float v = scp[0][lane] + scp[1][lane] + scp[2][lane] + scp[3][lane];
            float m = v;
            for (int off = 32; off > 0; off >>= 1) m = fmaxf(m, __shfl_xor(m, off, 64));
            float e = __expf(v - m);
            float ss = e;
            for (int off = 32; off > 0; off >>= 1) ss += __shfl_xor(ss, off, 64);
            a_l = e / ss;
        }
        {   // ctx partials: w covers s-range, lane covers d = lane*8..+8
            float cp[8] = {0, 0, 0, 0, 0, 0, 0, 0};
#pragma unroll 4
            for (int si = 0; si < 16; si++) {
                int s = w * 16 + si;
                float a = __shfl(a_l, s, 64);
                const float* ep = enc_out + ((size_t)(b * 64 + s)) * 512 + lane * 8;
                float4 e0 = *(const float4*)ep;
                float4 e1 = *(const float4*)(ep + 4);
                cp[0] += a * e0.x; cp[1] += a * e0.y; cp[2] += a * e0.z; cp[3] += a * e0.w;
                cp[4] += a * e1.x; cp[5] += a * e1.y; cp[6] += a * e1.z; cp[7] += a * e1.w;
            }
#pragma unroll
            for (int j = 0; j < 8; j++) fscr[w * 528 + j * 66 + lane] = cp[j];
        }
        __syncthreads();
        {   // reduce 4 partials, write ctx (coherent write-through store)
            int l0 = tid >> 2, j0 = (2 * tid) & 7;
            float v0 = fscr[j0 * 66 + l0] + fscr[528 + j0 * 66 + l0] +
                       fscr[1056 + j0 * 66 + l0] + fscr[1584 + j0 * 66 + l0];
            float v1 = fscr[(j0 + 1) * 66 + l0] + fscr[528 + (j0 + 1) * 66 + l0] +
                       fscr[1056 + (j0 + 1) * 66 + l0] + fscr[1584 + (j0 + 1) * 66 + l0];
            unsigned pack = (unsigned)f32_to_bf16_rne(v0) |
                            ((unsigned)f32_to_bf16_rne(v1) << 16);
            stg_coh_u32(ctxb + b * 512 + tid * 2, pack);
        }

        // ---- barrier 1: drain stores, arrive, per-wave partial wait ----
        bcnt++;
        wait_vm0();
        __syncthreads();
        if (tid == 0)
            __hip_atomic_store(&flags[bk * 32], bcnt, __ATOMIC_RELAXED,
                               __HIP_MEMORY_SCOPE_AGENT);
        if (kq == 0) {
            const unsigned* f = &flags[(w * 16 + col) * 32];
            while (__hip_atomic_load(f, __ATOMIC_RELAXED, __HIP_MEMORY_SCOPE_AGENT) < bcnt)
                __builtin_amdgcn_s_sleep(2);
        }

        // ---------------- phase 3: gates MFMA + in-register LSTM ----------------
        f32x4 acc0 = {0.f, 0.f, 0.f, 0.f};
        f32x4 acc1 = {0.f, 0.f, 0.f, 0.f};
        {
            uint4 cfr[16];
            const unsigned short* arow_c = ctxb + (size_t)(w * 16 + col) * 512 + kq * 8;
#pragma unroll
            for (int j = 0; j < 16; j++) ldg_coh_x4(&cfr[j], arow_c + j * 32);

            int sw0 = col & 7;
#pragma unroll
            for (int ks = 16; ks < 32; ks++) {
                BF8 a8; a8.q = hfr[ks - 16];
                int c = kq + 4 * ks;
                bf16x8 bf0 = *reinterpret_cast<const bf16x8*>(
                    Wlds + col * 1024 + ((c ^ sw0) * 8));
                bf16x8 bf1 = *reinterpret_cast<const bf16x8*>(
                    Wlds + (16 + col) * 1024 + ((c ^ sw0) * 8));
                acc0 = __builtin_amdgcn_mfma_f32_16x16x32_bf16(a8.v, bf0, acc0, 0, 0, 0);
                acc1 = __builtin_amdgcn_mfma_f32_16x16x32_bf16(a8.v, bf1, acc1, 0, 0, 0);
            }
            wait_vm0();
#pragma unroll
            for (int ks = 0; ks < 16; ks++) {
                BF8 a8; a8.q = cfr[ks];
                int c = kq + 4 * ks;
                bf16x8 bf0 = *reinterpret_cast<const bf16x8*>(
                    Wlds + col * 1024 + ((c ^ sw0) * 8));
                bf16x8 bf1 = *reinterpret_cast<const bf16x8*>(
                    Wlds + (16 + col) * 1024 + ((c ^ sw0) * 8));
                acc0 = __builtin_amdgcn_mfma_f32_16x16x32_bf16(a8.v, bf0, acc0, 0, 0, 0);
                acc1 = __builtin_amdgcn_mfma_f32_16x16x32_bf16(a8.v, bf1, acc1, 0, 0, 0);
            }
        }
        {   // gates + in-register LSTM (shfl_xor(8) exchange)
            float go0[4], go1[4];
            float geAv[4] = {geA4.x, geA4.y, geA4.z, geA4.w};
            float geBv[4] = {geB4.x, geB4.y, geB4.z, geB4.w};
#pragma unroll
            for (int rg = 0; rg < 4; rg++) {
                go0[rg] = acc0[rg] + geAv[rg];
                go1[rg] = acc1[rg] + geBv[rg];
            }
            float sh0 = __shfl_xor(r01 ? go0[2] : go0[0], 8, 64);
            float sh1 = __shfl_xor(r01 ? go0[3] : go0[1], 8, 64);
            float sh2 = __shfl_xor(r01 ? go1[2] : go1[0], 8, 64);
            float sh3 = __shfl_xor(r01 ? go1[3] : go1[1], 8, 64);
            int u = u0 + uloc;
            int bA = b0 + (r01 ? 0 : 2);
            {
                float G0 = r01 ? go0[0] : sh0;
                float G1 = r01 ? sh0 : go0[2];
                float G2 = r01 ? go1[0] : sh2;
                float G3 = r01 ? sh2 : go1[2];
                float ig = 1.f / (1.f + __expf(-G0));
                float fg = 1.f / (1.f + __expf(-G1));
                float gt = tanhf(G2);
                float og = 1.f / (1.f + __expf(-G3));
                creg0 = fg * creg0 + ig * gt;
                float hn = og * tanhf(creg0);
                unsigned short hv = f32_to_bf16_rne(hn);
                stg_coh_u16(hnxt + bA * 512 + u, (unsigned)hv);
                hseqb[((size_t)bA * T + t) * 512 + u] = hv;
            }
            {
                float G0 = r01 ? go0[1] : sh1;
                float G1 = r01 ? sh1 : go0[3];
                float G2 = r01 ? go1[1] : sh3;
                float G3 = r01 ? sh3 : go1[3];
                float ig = 1.f / (1.f + __expf(-G0));
                float fg = 1.f / (1.f + __expf(-G1));
                float gt = tanhf(G2);
                float og = 1.f / (1.f + __expf(-G3));
                creg1 = fg * creg1 + ig * gt;
                float hn = og * tanhf(creg1);
                unsigned short hv = f32_to_bf16_rne(hn);
                int bB = bA + 1;
                stg_coh_u16(hnxt + bB * 512 + u, (unsigned)hv);
                hseqb[((size_t)bB * T + t) * 512 + u] = hv;
            }
        }

        // ---- barrier 2: full (h is all-to-all); skip after last step ----
        bcnt++;
        if (t < T - 1) {
            wait_vm0();
            __syncthreads();
            if (tid == 0)
                __hip_atomic_store(&flags[bk * 32], bcnt, __ATOMIC_RELAXED,
                                   __HIP_MEMORY_SCOPE_AGENT);
            if (tid < 64) {
                const unsigned* f = &flags[tid * 32];
                while (__hip_atomic_load(f, __ATOMIC_RELAXED, __HIP_MEMORY_SCOPE_AGENT) < bcnt)
                    __builtin_amdgcn_s_sleep(2);
            }
            __syncthreads();
        }
    }
}

// ---------------------------------------------------------------------------
// Projection + exp-sum (R10-proven, unchanged).
// ---------------------------------------------------------------------------
__global__ __launch_bounds__(256) void proj_mfma_kernel(
        const unsigned short* __restrict__ hseqb,
        const float* __restrict__ proj_w,
        const float* __restrict__ proj_b,
        float* __restrict__ partial) {
    int tid = threadIdx.x;
    int wv = tid >> 6, lane = tid & 63;
    int col = lane & 15, kq = lane >> 4;
    int nhalf = wv & 1, mhalf = wv >> 1;
    int n0 = blockIdx.x * 64 + nhalf * 32;

    bf16x8 Af0[16], Af1[16];
    {
        const float* w0 = proj_w + (size_t)(n0 + col) * 512 + kq * 8;
        const float* w1 = proj_w + (size_t)(n0 + 16 + col) * 512 + kq * 8;
#pragma unroll
        for (int ks = 0; ks < 16; ks++) {
            Af0[ks] = cvt8(w0 + ks * 32);
            Af1[ks] = cvt8(w1 + ks * 32);
        }
    }
    float4 bias0 = *(const float4*)(proj_b + n0 + kq * 4);
    float4 bias1 = *(const float4*)(proj_b + n0 + 16 + kq * 4);

    __shared__ __attribute__((aligned(16))) unsigned short alds[32 * 512];
    __shared__ float esum[1344];
    for (int i = tid; i < 1344; i += 256) esum[i] = 0.f;
    __syncthreads();

    for (int mt = 0; mt < 42; mt++) {
        int mA = mt * 32;
        __syncthreads();
#pragma unroll
        for (int i = 0; i < 8; i++) {
            int r = i * 4 + wv;                 // wave-uniform row
            int cs = lane ^ (r & 7);            // pre-swizzled source chunk
            __builtin_amdgcn_global_load_lds(
                (const __attribute__((address_space(1))) void*)
                    (hseqb + (size_t)(mA + r) * 512 + cs * 8),
                (__attribute__((address_space(3))) void*)(alds + r * 512),
                16, 0, 0);
        }
        asm volatile("s_waitcnt vmcnt(0)" ::: "memory");
        __syncthreads();
        int rr = mhalf * 16 + col;
        int sw = rr & 7;
        f32x4 acc0 = {0.f, 0.f, 0.f, 0.f};
        f32x4 acc1 = {0.f, 0.f, 0.f, 0.f};
#pragma unroll
        for (int ks = 0; ks < 16; ks++) {
            int c = kq + 4 * ks;
            bf16x8 bf = *reinterpret_cast<const bf16x8*>(
                alds + rr * 512 + ((c ^ sw) * 8));
            acc0 = __builtin_amdgcn_mfma_f32_16x16x32_bf16(Af0[ks], bf, acc0, 0, 0, 0);
            acc1 = __builtin_amdgcn_mfma_f32_16x16x32_bf16(Af1[ks], bf, acc1, 0, 0, 0);
        }
        float e = __expf(acc0[0] + bias0.x) + __expf(acc0[1] + bias0.y) +
                  __expf(acc0[2] + bias0.z) + __expf(acc0[3] + bias0.w) +
                  __expf(acc1[0] + bias1.x) + __expf(acc1[1] + bias1.y) +
                  __expf(acc1[2] + bias1.z) + __expf(acc1[3] + bias1.w);
        atomicAdd(&esum[mA + rr], e);
    }
    __syncthreads();
    for (int i = tid; i < 1344; i += 256)
        partial[(size_t)blockIdx.x * 1344 + i] = esum[i];
}

// ---------------------------------------------------------------------------
// Fused loss: grid(1344) x block(64). Block (b*T+t):
//  1) sumexp over 500 partial blocks (lane-strided + butterfly)
//  2) label-row dot + masked nll -> nll2 (coherent store)
//  3) last-arriver (relaxed fetch_add; NO spinning -> deadlock-free under
//     any scheduling) reads all nll2 coherently and writes the scalar loss.
//  `old % 1344` guards rocprof replays that skip setup's counter re-zero.
// ---------------------------------------------------------------------------
__global__ __launch_bounds__(64) void loss_fused_kernel(
        const float* __restrict__ partial,
        const unsigned short* __restrict__ hseqb,
        const float* __restrict__ proj_w, const float* __restrict__ proj_b,
        const int* __restrict__ seq_label,
        float2* __restrict__ nll2, unsigned* __restrict__ done,
        float* __restrict__ out) {
    int bid = blockIdx.x;            // = b*T + t = m
    int lane = threadIdx.x;

    float s = 0.f;
    for (int nb = lane; nb < 500; nb += 64)
        s += partial[(size_t)nb * 1344 + bid];
    for (int off = 32; off > 0; off >>= 1) s += __shfl_xor(s, off, 64);

    int label = seq_label[bid];
    const unsigned short* hp = hseqb + (size_t)bid * 512;
    const float* wp = proj_w + (size_t)label * 512;
    float acc = 0.f;
#pragma unroll
    for (int i = 0; i < 8; i++)
        acc += bf16_to_f32(hp[lane + 64 * i]) * wp[lane + 64 * i];
    for (int off = 32; off > 0; off >>= 1) acc += __shfl_xor(acc, off, 64);

    if (lane == 0) {
        float mask = (label > 0) ? 1.f : 0.f;
        float nll = logf(s) - (acc + proj_b[label]);
        stg_coh_x2(&nll2[bid], make_float2(mask * nll, mask));
    }
    wait_vm0();                      // nll2 at coherence point before arrive

    unsigned old = 0;
    if (lane == 0)
        old = __hip_atomic_fetch_add(done, 1u, __ATOMIC_RELAXED,
                                     __HIP_MEMORY_SCOPE_AGENT);
    old = __shfl(old, 0, 64);
    if (old % 1344u == 1343u) {      // last arriver finalizes; b = lane
        float2 vv[T];
#pragma unroll
        for (int t = 0; t < T; t++)
            ldg_coh_x2(&vv[t], &nll2[lane * T + t]);
        wait_vm0();
        float num = 0.f, den = 0.f;
#pragma unroll
        for (int t = 0; t < T; t++) { num += vv[t].x; den += vv[t].y; }
        float l = (num / (den + 1e-6f)) * (1.f / 64.f);
        for (int off = 32; off > 0; off >>= 1) l += __shfl_xor(l, off, 64);
        if (lane == 0) *out = l;
    }
}

// ---------------------------------------------------------------------------
extern "C" void kernel_launch(void* const* d_in, const int* in_sizes, int n_in,
                              void* d_out, int out_size, void* d_ws, size_t ws_size,
                              hipStream_t stream) {
    const float* enc_h     = (const float*)d_in[0];
    const float* enc_out   = (const float*)d_in[1];
    const int*   seq_label = (const int*)d_in[3];
    const int*   dec_in    = (const int*)d_in[4];
    const float* style     = (const float*)d_in[5];
    const float* W_e2d_w   = (const float*)d_in[6];
    const float* W_e2d_b   = (const float*)d_in[7];
    const float* attn_W    = (const float*)d_in[8];
    const float* emb_table = (const float*)d_in[9];
    const float* w_ih      = (const float*)d_in[10];
    const float* w_hh      = (const float*)d_in[11];
    const float* b_ih      = (const float*)d_in[12];
    const float* b_hh      = (const float*)d_in[13];
    const float* proj_w    = (const float*)d_in[14];
    const float* proj_b    = (const float*)d_in[15];
    float* out = (float*)d_out;

    char* p = (char*)d_ws;
    float* partial = (float*)p;                    p += 500 * 1344 * 4;
    float* geT     = (float*)p;                    p += (size_t)21 * 2048 * 64 * 4;
    unsigned short* M_bf  = (unsigned short*)p;    p += (size_t)4096 * 512 * 2;
    unsigned short* wc2   = (unsigned short*)p;    p += (size_t)2048 * 1024 * 2;
    unsigned short* hseqb = (unsigned short*)p;    p += (size_t)1344 * 512 * 2;
    unsigned short* hb0   = (unsigned short*)p;    p += 64 * 512 * 2;
    unsigned short* hb1   = (unsigned short*)p;    p += 64 * 512 * 2;
    unsigned short* ctxb  = (unsigned short*)p;    p += 64 * 512 * 2;
    unsigned* bar = (unsigned*)p;                  p += 64 * 32 * 4;   // flag lines
    unsigned* done = (unsigned*)p;                 p += 64 * 4;        // arrive ctr
    float2* nll2 = (float2*)p;                     p += 1344 * 8;

    // 4 graph nodes total (was 8): setup zeroes bar+done; loss_fused
    // overwrites out (no memset nodes; sumexp/loss merged).
    setup_kernel<<<3296, 256, 0, stream>>>(enc_h, style, W_e2d_w, W_e2d_b,
                                           enc_out, attn_W, w_ih, w_hh,
                                           emb_table, dec_in, b_ih, b_hh,
                                           hb0, wc2, M_bf, geT, bar);

    scan_kernel<<<64, 256, 0, stream>>>(M_bf, enc_out, wc2, geT,
                                        hb0, hb1, ctxb, hseqb, bar);

    proj_mfma_kernel<<<500, 256, 0, stream>>>(hseqb, proj_w, proj_b, partial);

    loss_fused_kernel<<<1344, 64, 0, stream>>>(partial, hseqb, proj_w, proj_b,
                                               seq_label, nll2, done, out);
}